// Round 1
// baseline (2396.726 us; speedup 1.0000x reference)
//
#include <hip/hip_runtime.h>

#define N_NODES 100000
#define N_EDGES 1200000
#define HID 64
#define NGRAPH 512
#define NCLS 2
#define BN_EPS 1e-5f

// ---------------- kernels ----------------

// x[i][d] = shape_W[sid[i]][d] + col_W[cid[i]][d]   (float4 per thread)
__global__ void k_embed(const int* __restrict__ sid, const int* __restrict__ cid,
                        const float* __restrict__ sW, const float* __restrict__ cW,
                        float* __restrict__ x) {
    int idx = blockIdx.x * blockDim.x + threadIdx.x;   // over N*16
    if (idx >= N_NODES * 16) return;
    int i = idx >> 4, q = idx & 15;
    float4 s = *(const float4*)&sW[sid[i] * HID + q * 4];
    float4 c = *(const float4*)&cW[cid[i] * HID + q * 4];
    float4 r = make_float4(s.x + c.x, s.y + c.y, s.z + c.z, s.w + c.w);
    *(float4*)&x[i * HID + q * 4] = r;
}

// msg[dst] += x[src]; cnt[dst] += 1   (16 threads per edge, float4 gather, scalar atomics)
__global__ void k_aggregate(const int* __restrict__ src, const int* __restrict__ dst,
                            const float* __restrict__ x, float* __restrict__ msg,
                            int* __restrict__ cnt, int do_cnt) {
    int idx = blockIdx.x * blockDim.x + threadIdx.x;   // over E*16
    if (idx >= N_EDGES * 16) return;
    int e = idx >> 4, q = idx & 15;
    int s = src[e], d = dst[e];
    float4 v = *(const float4*)&x[s * HID + q * 4];
    float* m = &msg[d * HID + q * 4];
    atomicAdd(m + 0, v.x);
    atomicAdd(m + 1, v.y);
    atomicAdd(m + 2, v.z);
    atomicAdd(m + 3, v.w);
    if (do_cnt && q == 0) atomicAdd(&cnt[d], 1);
}

// h = mean @ Wl + b + x @ Wr, written in-place into msg; also accumulate per-column
// sum and sum-of-squares for BN. 4 nodes per 256-thread block, grid-stride.
__global__ __launch_bounds__(256) void k_sage_linear(
    const float* __restrict__ x, float* __restrict__ msg, const int* __restrict__ cnt,
    const float* __restrict__ Wl, const float* __restrict__ bl, const float* __restrict__ Wr,
    float* __restrict__ sums, float* __restrict__ sumsq) {
    __shared__ float sWl[HID * HID];
    __shared__ float sWr[HID * HID];
    __shared__ float sm[4][HID];
    __shared__ float sx[4][HID];
    int tid = threadIdx.x;
    for (int t = tid; t < HID * HID; t += 256) { sWl[t] = Wl[t]; sWr[t] = Wr[t]; }
    __syncthreads();
    int li = tid >> 6;   // node slot 0..3
    int d  = tid & 63;   // output dim
    float bias = bl[d];
    float accs = 0.f, accq = 0.f;
    for (int base = blockIdx.x * 4; base < N_NODES; base += gridDim.x * 4) {
        int i = base + li;
        if (i < N_NODES) {
            float inv = 1.f / fmaxf((float)cnt[i], 1.f);
            sm[li][d] = msg[i * HID + d] * inv;   // mean row
            sx[li][d] = x[i * HID + d];
        }
        __syncthreads();
        if (i < N_NODES) {
            float h = bias;
            #pragma unroll
            for (int k = 0; k < HID; ++k) {
                h += sm[li][k] * sWl[k * HID + d] + sx[li][k] * sWr[k * HID + d];
            }
            msg[i * HID + d] = h;    // safe: whole row already staged to LDS
            accs += h;
            accq += h * h;
        }
        __syncthreads();
    }
    // reduce the 4 node-slots per column, one atomic per column per block
    sm[li][d] = accs;
    sx[li][d] = accq;
    __syncthreads();
    if (li == 0) {
        float s = sm[0][d] + sm[1][d] + sm[2][d] + sm[3][d];
        float q = sx[0][d] + sx[1][d] + sx[2][d] + sx[3][d];
        atomicAdd(&sums[d], s);
        atomicAdd(&sumsq[d], q);
    }
}

// per-column BN affine params: y = h*scale + shift
__global__ void k_bn_params(const float* __restrict__ sums, const float* __restrict__ sumsq,
                            const float* __restrict__ g, const float* __restrict__ be,
                            float* __restrict__ scale, float* __restrict__ shift) {
    int d = threadIdx.x;
    if (d >= HID) return;
    float mu  = sums[d] * (1.f / N_NODES);
    float var = sumsq[d] * (1.f / N_NODES) - mu * mu;
    float sc  = g[d] * rsqrtf(var + BN_EPS);
    scale[d] = sc;
    shift[d] = be[d] - mu * sc;
}

// out = relu(h*scale + shift)
__global__ void k_bn_relu(const float* __restrict__ h, const float* __restrict__ scale,
                          const float* __restrict__ shift, float* __restrict__ out) {
    int idx = blockIdx.x * blockDim.x + threadIdx.x;   // over N*HID
    if (idx >= N_NODES * HID) return;
    int d = idx & 63;
    out[idx] = fmaxf(h[idx] * scale[d] + shift[d], 0.f);
}

// global add pool; batch sorted -> running accumulator, flush on graph change
__global__ void k_pool(const float* __restrict__ x, const int* __restrict__ batch,
                       float* __restrict__ graph_x) {
    int d = threadIdx.x;   // 64 threads
    int chunk = (N_NODES + gridDim.x - 1) / gridDim.x;
    int a = blockIdx.x * chunk;
    int b = min(a + chunk, N_NODES);
    if (a >= b) return;
    int cur = batch[a];
    float acc = 0.f;
    for (int i = a; i < b; ++i) {
        int g = batch[i];
        if (g != cur) {
            atomicAdd(&graph_x[cur * HID + d], acc);
            acc = 0.f;
            cur = g;
        }
        acc += x[i * HID + d];
    }
    atomicAdd(&graph_x[cur * HID + d], acc);
}

// out[g][c] = graph_x[g] . Wlin[:,c] + blin[c]
__global__ void k_cls(const float* __restrict__ graph_x, const float* __restrict__ Wlin,
                      const float* __restrict__ blin, float* __restrict__ out) {
    int idx = blockIdx.x * blockDim.x + threadIdx.x;
    if (idx >= NGRAPH * NCLS) return;
    int g = idx / NCLS, c = idx % NCLS;
    float acc = blin[c];
    #pragma unroll
    for (int k = 0; k < HID; ++k) acc += graph_x[g * HID + k] * Wlin[k * NCLS + c];
    out[idx] = acc;
}

// ---------------- launch ----------------

extern "C" void kernel_launch(void* const* d_in, const int* in_sizes, int n_in,
                              void* d_out, int out_size, void* d_ws, size_t ws_size,
                              hipStream_t stream) {
    const int*   sid   = (const int*)d_in[0];
    const int*   cid   = (const int*)d_in[1];
    const int*   esrc  = (const int*)d_in[2];
    const int*   edst  = esrc + N_EDGES;
    const int*   batch = (const int*)d_in[3];
    const float* sW    = (const float*)d_in[4];
    const float* cW    = (const float*)d_in[5];
    const float* W1l   = (const float*)d_in[6];
    const float* b1    = (const float*)d_in[7];
    const float* W1r   = (const float*)d_in[8];
    const float* g1    = (const float*)d_in[9];
    const float* be1   = (const float*)d_in[10];
    const float* W2l   = (const float*)d_in[11];
    const float* b2    = (const float*)d_in[12];
    const float* W2r   = (const float*)d_in[13];
    const float* g2    = (const float*)d_in[14];
    const float* be2   = (const float*)d_in[15];
    const float* Wlin  = (const float*)d_in[16];
    const float* blin  = (const float*)d_in[17];
    float* out = (float*)d_out;

    // workspace layout
    char* ws = (char*)d_ws;
    float* xbuf  = (float*)ws;                                   // N*HID
    float* msg   = xbuf + (size_t)N_NODES * HID;                 // N*HID (also h, in place)
    int*   cnt   = (int*)(msg + (size_t)N_NODES * HID);          // N
    float* sums  = (float*)(cnt + N_NODES);                      // HID
    float* sumsq = sums + HID;                                   // HID
    float* scale = sumsq + HID;                                  // HID
    float* shift = scale + HID;                                  // HID
    float* graph_x = shift + HID;                                // NGRAPH*HID

    const size_t featBytes = (size_t)N_NODES * HID * sizeof(float);

    // ---- embed ----
    k_embed<<<(N_NODES * 16 + 255) / 256, 256, 0, stream>>>(sid, cid, sW, cW, xbuf);

    // ---- layer 1 ----
    hipMemsetAsync(msg, 0, featBytes, stream);
    hipMemsetAsync(cnt, 0, N_NODES * sizeof(int), stream);
    hipMemsetAsync(sums, 0, 2 * HID * sizeof(float), stream);
    k_aggregate<<<(N_EDGES * 16 + 255) / 256, 256, 0, stream>>>(esrc, edst, xbuf, msg, cnt, 1);
    k_sage_linear<<<2048, 256, 0, stream>>>(xbuf, msg, cnt, W1l, b1, W1r, sums, sumsq);
    k_bn_params<<<1, 64, 0, stream>>>(sums, sumsq, g1, be1, scale, shift);
    k_bn_relu<<<(N_NODES * HID + 255) / 256, 256, 0, stream>>>(msg, scale, shift, xbuf);

    // ---- layer 2 ----
    hipMemsetAsync(msg, 0, featBytes, stream);
    hipMemsetAsync(sums, 0, 2 * HID * sizeof(float), stream);
    k_aggregate<<<(N_EDGES * 16 + 255) / 256, 256, 0, stream>>>(esrc, edst, xbuf, msg, cnt, 0);
    k_sage_linear<<<2048, 256, 0, stream>>>(xbuf, msg, cnt, W2l, b2, W2r, sums, sumsq);
    k_bn_params<<<1, 64, 0, stream>>>(sums, sumsq, g2, be2, scale, shift);
    k_bn_relu<<<(N_NODES * HID + 255) / 256, 256, 0, stream>>>(msg, scale, shift, xbuf);

    // ---- pool + classifier ----
    hipMemsetAsync(graph_x, 0, (size_t)NGRAPH * HID * sizeof(float), stream);
    k_pool<<<512, 64, 0, stream>>>(xbuf, batch, graph_x);
    k_cls<<<(NGRAPH * NCLS + 255) / 256, 256, 0, stream>>>(graph_x, Wlin, blin, out);
}

// Round 2
// 711.001 us; speedup vs baseline: 3.3709x; 3.3709x over previous
//
#include <hip/hip_runtime.h>

#define N_NODES 100000
#define N_EDGES 1200000
#define HID 64
#define NGRAPH 512
#define NCLS 2
#define BN_EPS 1e-5f
#define WPAD 68   // transposed-weight row stride: 16B-aligned, conflict-minimal

// ---------------- embedding ----------------
// x[i][d] = shape_W[sid[i]][d] + col_W[cid[i]][d]   (float4 per thread)
__global__ void k_embed(const int* __restrict__ sid, const int* __restrict__ cid,
                        const float* __restrict__ sW, const float* __restrict__ cW,
                        float* __restrict__ x) {
    int idx = blockIdx.x * blockDim.x + threadIdx.x;   // over N*16
    if (idx >= N_NODES * 16) return;
    int i = idx >> 4, q = idx & 15;
    float4 s = *(const float4*)&sW[sid[i] * HID + q * 4];
    float4 c = *(const float4*)&cW[cid[i] * HID + q * 4];
    *(float4*)&x[i * HID + q * 4] = make_float4(s.x + c.x, s.y + c.y, s.z + c.z, s.w + c.w);
}

// ---------------- CSR build ----------------
__global__ void k_hist(const int* __restrict__ dst, int* __restrict__ deg) {
    int e = blockIdx.x * blockDim.x + threadIdx.x;
    if (e < N_EDGES) atomicAdd(&deg[dst[e]], 1);
}

// one-block exclusive scan of deg[0..N) -> row_ptr[0..N], cursor copy
__global__ __launch_bounds__(1024) void k_scan(const int* __restrict__ deg,
                                               int* __restrict__ row_ptr,
                                               int* __restrict__ cursor) {
    __shared__ int part[1024];
    int t = threadIdx.x;
    const int CH = (N_NODES + 1023) / 1024;   // 98
    int a = t * CH, b = min(a + CH, N_NODES);
    int s = 0;
    for (int j = a; j < b; ++j) s += deg[j];
    part[t] = s;
    __syncthreads();
    for (int off = 1; off < 1024; off <<= 1) {
        int v = part[t];
        int u = (t >= off) ? part[t - off] : 0;
        __syncthreads();
        part[t] = v + u;
        __syncthreads();
    }
    int pre = (t == 0) ? 0 : part[t - 1];
    for (int j = a; j < b; ++j) {
        row_ptr[j] = pre; cursor[j] = pre;
        pre += deg[j];
    }
    if (t == 1023) row_ptr[N_NODES] = pre;   // == E
}

__global__ void k_scatter(const int* __restrict__ src, const int* __restrict__ dst,
                          int* __restrict__ cursor, int* __restrict__ csr_src) {
    int e = blockIdx.x * blockDim.x + threadIdx.x;
    if (e >= N_EDGES) return;
    int slot = atomicAdd(&cursor[dst[e]], 1);
    csr_src[slot] = src[e];
}

// ---------------- fused SAGE layer: gather-mean + 2x GEMV + BN stats ----------------
// 4 waves/block; each wave owns a quad of 4 nodes per iteration.
__global__ __launch_bounds__(256) void k_sage_fused(
    const float* __restrict__ x, const int* __restrict__ row_ptr,
    const int* __restrict__ csr_src,
    const float* __restrict__ Wl, const float* __restrict__ bl,
    const float* __restrict__ Wr,
    float* __restrict__ h_out, float* __restrict__ sums, float* __restrict__ sumsq) {
    __shared__ float sWlT[HID * WPAD];   // [d][k], transposed, padded
    __shared__ float sWrT[HID * WPAD];
    __shared__ float smean[4][4][HID];   // [wave][node][dim]
    __shared__ float sxr[4][4][HID];
    int tid = threadIdx.x;
    for (int t = tid; t < HID * HID; t += 256) {
        int k = t >> 6, dd = t & 63;
        sWlT[dd * WPAD + k] = Wl[t];     // Wl[k][dd], coalesced read
        sWrT[dd * WPAD + k] = Wr[t];
    }
    __syncthreads();
    int wv = tid >> 6, d = tid & 63;
    float bias = bl[d];
    float accs = 0.f, accq = 0.f;
    const int quads = N_NODES / 4;       // 25000, exact
    for (int q = blockIdx.x * 4 + wv; q < quads; q += gridDim.x * 4) {
        int base = q * 4;
        float hv[4];
        #pragma unroll
        for (int n = 0; n < 4; ++n) {
            int i = base + n;
            int beg = row_ptr[i], end = row_ptr[i + 1];
            float m0 = 0.f, m1 = 0.f, m2 = 0.f, m3 = 0.f;
            int e = beg;
            for (; e + 4 <= end; e += 4) {      // 4 gathers in flight
                int s0 = csr_src[e], s1 = csr_src[e + 1];
                int s2 = csr_src[e + 2], s3 = csr_src[e + 3];
                m0 += x[(size_t)s0 * HID + d];
                m1 += x[(size_t)s1 * HID + d];
                m2 += x[(size_t)s2 * HID + d];
                m3 += x[(size_t)s3 * HID + d];
            }
            for (; e < end; ++e) m0 += x[(size_t)csr_src[e] * HID + d];
            int deg = end - beg;
            smean[wv][n][d] = ((m0 + m1) + (m2 + m3)) / (float)max(deg, 1);
            sxr[wv][n][d]   = x[(size_t)i * HID + d];
            hv[n] = bias;
        }
        // wave-private LDS: producer==consumer wave, no block barrier needed
        #pragma unroll
        for (int kq = 0; kq < 16; ++kq) {
            float4 wl = *(const float4*)&sWlT[d * WPAD + kq * 4];
            float4 wr = *(const float4*)&sWrT[d * WPAD + kq * 4];
            #pragma unroll
            for (int n = 0; n < 4; ++n) {
                float4 mm = *(const float4*)&smean[wv][n][kq * 4];
                float4 xx = *(const float4*)&sxr[wv][n][kq * 4];
                hv[n] += mm.x * wl.x + mm.y * wl.y + mm.z * wl.z + mm.w * wl.w
                       + xx.x * wr.x + xx.y * wr.y + xx.z * wr.z + xx.w * wr.w;
            }
        }
        #pragma unroll
        for (int n = 0; n < 4; ++n) {
            h_out[(size_t)(base + n) * HID + d] = hv[n];
            accs += hv[n];
            accq += hv[n] * hv[n];
        }
    }
    __syncthreads();
    smean[wv][0][d] = accs;
    sxr[wv][0][d]   = accq;
    __syncthreads();
    if (wv == 0) {
        atomicAdd(&sums[d],  smean[0][0][d] + smean[1][0][d] + smean[2][0][d] + smean[3][0][d]);
        atomicAdd(&sumsq[d], sxr[0][0][d] + sxr[1][0][d] + sxr[2][0][d] + sxr[3][0][d]);
    }
}

// ---------------- BN ----------------
__global__ void k_bn_params(const float* __restrict__ sums, const float* __restrict__ sumsq,
                            const float* __restrict__ g, const float* __restrict__ be,
                            float* __restrict__ scale, float* __restrict__ shift) {
    int d = threadIdx.x;
    if (d >= HID) return;
    float mu  = sums[d] * (1.f / N_NODES);
    float var = sumsq[d] * (1.f / N_NODES) - mu * mu;
    float sc  = g[d] * rsqrtf(var + BN_EPS);
    scale[d] = sc;
    shift[d] = be[d] - mu * sc;
}

__global__ void k_bn_relu(const float* __restrict__ h, const float* __restrict__ scale,
                          const float* __restrict__ shift, float* __restrict__ out) {
    int idx = blockIdx.x * blockDim.x + threadIdx.x;   // over N*16
    if (idx >= N_NODES * 16) return;
    int q = idx & 15;
    float4 hv = *(const float4*)&h[(size_t)idx * 4];
    float4 sc = *(const float4*)&scale[q * 4];
    float4 sh = *(const float4*)&shift[q * 4];
    float4 r;
    r.x = fmaxf(hv.x * sc.x + sh.x, 0.f);
    r.y = fmaxf(hv.y * sc.y + sh.y, 0.f);
    r.z = fmaxf(hv.z * sc.z + sh.z, 0.f);
    r.w = fmaxf(hv.w * sc.w + sh.w, 0.f);
    *(float4*)&out[(size_t)idx * 4] = r;
}

// ---------------- pool + classifier ----------------
__global__ void k_pool(const float* __restrict__ x, const int* __restrict__ batch,
                       float* __restrict__ graph_x) {
    int d = threadIdx.x;   // 64 threads
    int chunk = (N_NODES + gridDim.x - 1) / gridDim.x;
    int a = blockIdx.x * chunk;
    int b = min(a + chunk, N_NODES);
    if (a >= b) return;
    int cur = batch[a];
    float acc = 0.f;
    for (int i = a; i < b; ++i) {
        int g = batch[i];
        if (g != cur) {
            atomicAdd(&graph_x[cur * HID + d], acc);
            acc = 0.f;
            cur = g;
        }
        acc += x[(size_t)i * HID + d];
    }
    atomicAdd(&graph_x[cur * HID + d], acc);
}

__global__ void k_cls(const float* __restrict__ graph_x, const float* __restrict__ Wlin,
                      const float* __restrict__ blin, float* __restrict__ out) {
    int idx = blockIdx.x * blockDim.x + threadIdx.x;
    if (idx >= NGRAPH * NCLS) return;
    int g = idx / NCLS, c = idx % NCLS;
    float acc = blin[c];
    #pragma unroll
    for (int k = 0; k < HID; ++k) acc += graph_x[g * HID + k] * Wlin[k * NCLS + c];
    out[idx] = acc;
}

// ---------------- launch ----------------
extern "C" void kernel_launch(void* const* d_in, const int* in_sizes, int n_in,
                              void* d_out, int out_size, void* d_ws, size_t ws_size,
                              hipStream_t stream) {
    const int*   sid   = (const int*)d_in[0];
    const int*   cid   = (const int*)d_in[1];
    const int*   esrc  = (const int*)d_in[2];
    const int*   edst  = esrc + N_EDGES;
    const int*   batch = (const int*)d_in[3];
    const float* sW    = (const float*)d_in[4];
    const float* cW    = (const float*)d_in[5];
    const float* W1l   = (const float*)d_in[6];
    const float* b1    = (const float*)d_in[7];
    const float* W1r   = (const float*)d_in[8];
    const float* g1    = (const float*)d_in[9];
    const float* be1   = (const float*)d_in[10];
    const float* W2l   = (const float*)d_in[11];
    const float* b2    = (const float*)d_in[12];
    const float* W2r   = (const float*)d_in[13];
    const float* g2    = (const float*)d_in[14];
    const float* be2   = (const float*)d_in[15];
    const float* Wlin  = (const float*)d_in[16];
    const float* blin  = (const float*)d_in[17];
    float* out = (float*)d_out;

    // workspace layout
    char* ws = (char*)d_ws;
    float* xbuf    = (float*)ws;                                  // N*HID
    float* hbuf    = xbuf + (size_t)N_NODES * HID;                // N*HID
    int*   deg     = (int*)(hbuf + (size_t)N_NODES * HID);        // N
    int*   row_ptr = deg + N_NODES;                               // N+1
    int*   cursor  = row_ptr + N_NODES + 1;                       // N
    int*   csr_src = cursor + N_NODES;                            // E
    float* sums    = (float*)(csr_src + N_EDGES);                 // HID
    float* sumsq   = sums + HID;                                  // HID
    float* scale   = sumsq + HID;                                 // HID
    float* shift   = scale + HID;                                 // HID
    float* graph_x = shift + HID;                                 // NGRAPH*HID

    // ---- embed ----
    k_embed<<<(N_NODES * 16 + 255) / 256, 256, 0, stream>>>(sid, cid, sW, cW, xbuf);

    // ---- CSR build (reused by both layers) ----
    hipMemsetAsync(deg, 0, N_NODES * sizeof(int), stream);
    k_hist<<<(N_EDGES + 255) / 256, 256, 0, stream>>>(edst, deg);
    k_scan<<<1, 1024, 0, stream>>>(deg, row_ptr, cursor);
    k_scatter<<<(N_EDGES + 255) / 256, 256, 0, stream>>>(esrc, edst, cursor, csr_src);

    // ---- layer 1 ----
    hipMemsetAsync(sums, 0, 2 * HID * sizeof(float), stream);
    k_sage_fused<<<768, 256, 0, stream>>>(xbuf, row_ptr, csr_src, W1l, b1, W1r,
                                          hbuf, sums, sumsq);
    k_bn_params<<<1, 64, 0, stream>>>(sums, sumsq, g1, be1, scale, shift);
    k_bn_relu<<<(N_NODES * 16 + 255) / 256, 256, 0, stream>>>(hbuf, scale, shift, xbuf);

    // ---- layer 2 ----
    hipMemsetAsync(sums, 0, 2 * HID * sizeof(float), stream);
    k_sage_fused<<<768, 256, 0, stream>>>(xbuf, row_ptr, csr_src, W2l, b2, W2r,
                                          hbuf, sums, sumsq);
    k_bn_params<<<1, 64, 0, stream>>>(sums, sumsq, g2, be2, scale, shift);
    k_bn_relu<<<(N_NODES * 16 + 255) / 256, 256, 0, stream>>>(hbuf, scale, shift, xbuf);

    // ---- pool + classifier ----
    hipMemsetAsync(graph_x, 0, (size_t)NGRAPH * HID * sizeof(float), stream);
    k_pool<<<1024, 64, 0, stream>>>(xbuf, batch, graph_x);
    k_cls<<<(NGRAPH * NCLS + 255) / 256, 256, 0, stream>>>(graph_x, Wlin, blin, out);
}

// Round 3
// 505.283 us; speedup vs baseline: 4.7433x; 1.4071x over previous
//
#include <hip/hip_runtime.h>

#define N_NODES 100000
#define N_EDGES 1200000
#define HID 64
#define NGRAPH 512
#define NCLS 2
#define BN_EPS 1e-5f
#define WPAD 68   // transposed-weight row stride: 16B-aligned, conflict-minimal

#define SCAN_B 98          // ceil(100000/1024)
#define SCAN_T 1024

// ---------------- embedding ----------------
__global__ void k_embed(const int* __restrict__ sid, const int* __restrict__ cid,
                        const float* __restrict__ sW, const float* __restrict__ cW,
                        float* __restrict__ x) {
    int idx = blockIdx.x * blockDim.x + threadIdx.x;   // over N*16
    if (idx >= N_NODES * 16) return;
    int i = idx >> 4, q = idx & 15;
    float4 s = *(const float4*)&sW[sid[i] * HID + q * 4];
    float4 c = *(const float4*)&cW[cid[i] * HID + q * 4];
    *(float4*)&x[i * HID + q * 4] = make_float4(s.x + c.x, s.y + c.y, s.z + c.z, s.w + c.w);
}

// ---------------- CSR build ----------------
__global__ void k_hist(const int* __restrict__ dst, int* __restrict__ deg) {
    int e = blockIdx.x * blockDim.x + threadIdx.x;
    if (e < N_EDGES) atomicAdd(&deg[dst[e]], 1);
}

// pass 1: per-block inclusive scan; write exclusive prefix (block-local) + block total
__global__ __launch_bounds__(SCAN_T) void k_scan_part(const int* __restrict__ deg,
                                                      int* __restrict__ row_ptr,
                                                      int* __restrict__ blockSums) {
    __shared__ int sh[SCAN_T];
    int t = threadIdx.x;
    int i = blockIdx.x * SCAN_T + t;
    int v = (i < N_NODES) ? deg[i] : 0;
    sh[t] = v;
    __syncthreads();
    #pragma unroll
    for (int off = 1; off < SCAN_T; off <<= 1) {
        int cur = sh[t];
        int u = (t >= off) ? sh[t - off] : 0;
        __syncthreads();
        sh[t] = cur + u;
        __syncthreads();
    }
    if (i < N_NODES) row_ptr[i] = sh[t] - v;   // block-local exclusive
    if (t == SCAN_T - 1) blockSums[blockIdx.x] = sh[t];
}

// pass 2: scan the 98 block totals (one small block)
__global__ __launch_bounds__(128) void k_scan_mid(int* __restrict__ blockSums,
                                                  int* __restrict__ blockOff,
                                                  int* __restrict__ row_ptr) {
    __shared__ int sh[128];
    int t = threadIdx.x;
    int v = (t < SCAN_B) ? blockSums[t] : 0;
    sh[t] = v;
    __syncthreads();
    #pragma unroll
    for (int off = 1; off < 128; off <<= 1) {
        int cur = sh[t];
        int u = (t >= off) ? sh[t - off] : 0;
        __syncthreads();
        sh[t] = cur + u;
        __syncthreads();
    }
    if (t < SCAN_B) blockOff[t] = sh[t] - v;   // exclusive
    if (t == 0) row_ptr[N_NODES] = N_EDGES;    // grand total known statically
}

// pass 3: add block offsets; emit final row_ptr + cursor copy
__global__ __launch_bounds__(SCAN_T) void k_scan_add(int* __restrict__ row_ptr,
                                                     const int* __restrict__ blockOff,
                                                     int* __restrict__ cursor) {
    int i = blockIdx.x * SCAN_T + threadIdx.x;
    if (i >= N_NODES) return;
    int rp = row_ptr[i] + blockOff[blockIdx.x];
    row_ptr[i] = rp;
    cursor[i] = rp;
}

__global__ void k_scatter(const int* __restrict__ src, const int* __restrict__ dst,
                          int* __restrict__ cursor, int* __restrict__ csr_src) {
    int e = blockIdx.x * blockDim.x + threadIdx.x;
    if (e >= N_EDGES) return;
    int slot = atomicAdd(&cursor[dst[e]], 1);
    csr_src[slot] = src[e];
}

// ---------------- fused SAGE layer: gather-mean + 2x GEMV + BN stats ----------------
__global__ __launch_bounds__(256) void k_sage_fused(
    const float* __restrict__ x, const int* __restrict__ row_ptr,
    const int* __restrict__ csr_src,
    const float* __restrict__ Wl, const float* __restrict__ bl,
    const float* __restrict__ Wr,
    float* __restrict__ h_out, float* __restrict__ sums, float* __restrict__ sumsq) {
    __shared__ float sWlT[HID * WPAD];   // [d][k], transposed, padded
    __shared__ float sWrT[HID * WPAD];
    __shared__ float smean[4][4][HID];   // [wave][node][dim]
    __shared__ float sxr[4][4][HID];
    int tid = threadIdx.x;
    for (int t = tid; t < HID * HID; t += 256) {
        int k = t >> 6, dd = t & 63;
        sWlT[dd * WPAD + k] = Wl[t];
        sWrT[dd * WPAD + k] = Wr[t];
    }
    __syncthreads();
    int wv = tid >> 6, d = tid & 63;
    float bias = bl[d];
    float accs = 0.f, accq = 0.f;
    const int quads = N_NODES / 4;       // 25000, exact
    for (int q = blockIdx.x * 4 + wv; q < quads; q += gridDim.x * 4) {
        int base = q * 4;
        float hv[4];
        #pragma unroll
        for (int n = 0; n < 4; ++n) {
            int i = base + n;
            int beg = row_ptr[i], end = row_ptr[i + 1];
            float m0 = 0.f, m1 = 0.f, m2 = 0.f, m3 = 0.f;
            int e = beg;
            for (; e + 4 <= end; e += 4) {
                int s0 = csr_src[e], s1 = csr_src[e + 1];
                int s2 = csr_src[e + 2], s3 = csr_src[e + 3];
                m0 += x[(size_t)s0 * HID + d];
                m1 += x[(size_t)s1 * HID + d];
                m2 += x[(size_t)s2 * HID + d];
                m3 += x[(size_t)s3 * HID + d];
            }
            for (; e < end; ++e) m0 += x[(size_t)csr_src[e] * HID + d];
            int deg = end - beg;
            smean[wv][n][d] = ((m0 + m1) + (m2 + m3)) / (float)max(deg, 1);
            sxr[wv][n][d]   = x[(size_t)i * HID + d];
            hv[n] = bias;
        }
        #pragma unroll
        for (int kq = 0; kq < 16; ++kq) {
            float4 wl = *(const float4*)&sWlT[d * WPAD + kq * 4];
            float4 wr = *(const float4*)&sWrT[d * WPAD + kq * 4];
            #pragma unroll
            for (int n = 0; n < 4; ++n) {
                float4 mm = *(const float4*)&smean[wv][n][kq * 4];
                float4 xx = *(const float4*)&sxr[wv][n][kq * 4];
                hv[n] += mm.x * wl.x + mm.y * wl.y + mm.z * wl.z + mm.w * wl.w
                       + xx.x * wr.x + xx.y * wr.y + xx.z * wr.z + xx.w * wr.w;
            }
        }
        #pragma unroll
        for (int n = 0; n < 4; ++n) {
            h_out[(size_t)(base + n) * HID + d] = hv[n];
            accs += hv[n];
            accq += hv[n] * hv[n];
        }
    }
    __syncthreads();
    smean[wv][0][d] = accs;
    sxr[wv][0][d]   = accq;
    __syncthreads();
    if (wv == 0) {
        atomicAdd(&sums[d],  smean[0][0][d] + smean[1][0][d] + smean[2][0][d] + smean[3][0][d]);
        atomicAdd(&sumsq[d], sxr[0][0][d] + sxr[1][0][d] + sxr[2][0][d] + sxr[3][0][d]);
    }
}

// ---------------- BN ----------------
__global__ void k_bn_params(const float* __restrict__ sums, const float* __restrict__ sumsq,
                            const float* __restrict__ g, const float* __restrict__ be,
                            float* __restrict__ scale, float* __restrict__ shift) {
    int d = threadIdx.x;
    if (d >= HID) return;
    float mu  = sums[d] * (1.f / N_NODES);
    float var = sumsq[d] * (1.f / N_NODES) - mu * mu;
    float sc  = g[d] * rsqrtf(var + BN_EPS);
    scale[d] = sc;
    shift[d] = be[d] - mu * sc;
}

__global__ void k_bn_relu(const float* __restrict__ h, const float* __restrict__ scale,
                          const float* __restrict__ shift, float* __restrict__ out) {
    int idx = blockIdx.x * blockDim.x + threadIdx.x;   // over N*16
    if (idx >= N_NODES * 16) return;
    int q = idx & 15;
    float4 hv = *(const float4*)&h[(size_t)idx * 4];
    float4 sc = *(const float4*)&scale[q * 4];
    float4 sh = *(const float4*)&shift[q * 4];
    float4 r;
    r.x = fmaxf(hv.x * sc.x + sh.x, 0.f);
    r.y = fmaxf(hv.y * sc.y + sh.y, 0.f);
    r.z = fmaxf(hv.z * sc.z + sh.z, 0.f);
    r.w = fmaxf(hv.w * sc.w + sh.w, 0.f);
    *(float4*)&out[(size_t)idx * 4] = r;
}

// ---------------- pool + classifier ----------------
__global__ void k_pool(const float* __restrict__ x, const int* __restrict__ batch,
                       float* __restrict__ graph_x) {
    int d = threadIdx.x;   // 64 threads
    int chunk = (N_NODES + gridDim.x - 1) / gridDim.x;
    int a = blockIdx.x * chunk;
    int b = min(a + chunk, N_NODES);
    if (a >= b) return;
    int cur = batch[a];
    float acc = 0.f;
    for (int i = a; i < b; ++i) {
        int g = batch[i];
        if (g != cur) {
            atomicAdd(&graph_x[cur * HID + d], acc);
            acc = 0.f;
            cur = g;
        }
        acc += x[(size_t)i * HID + d];
    }
    atomicAdd(&graph_x[cur * HID + d], acc);
}

__global__ void k_cls(const float* __restrict__ graph_x, const float* __restrict__ Wlin,
                      const float* __restrict__ blin, float* __restrict__ out) {
    int idx = blockIdx.x * blockDim.x + threadIdx.x;
    if (idx >= NGRAPH * NCLS) return;
    int g = idx / NCLS, c = idx % NCLS;
    float acc = blin[c];
    #pragma unroll
    for (int k = 0; k < HID; ++k) acc += graph_x[g * HID + k] * Wlin[k * NCLS + c];
    out[idx] = acc;
}

// ---------------- launch ----------------
extern "C" void kernel_launch(void* const* d_in, const int* in_sizes, int n_in,
                              void* d_out, int out_size, void* d_ws, size_t ws_size,
                              hipStream_t stream) {
    const int*   sid   = (const int*)d_in[0];
    const int*   cid   = (const int*)d_in[1];
    const int*   esrc  = (const int*)d_in[2];
    const int*   edst  = esrc + N_EDGES;
    const int*   batch = (const int*)d_in[3];
    const float* sW    = (const float*)d_in[4];
    const float* cW    = (const float*)d_in[5];
    const float* W1l   = (const float*)d_in[6];
    const float* b1    = (const float*)d_in[7];
    const float* W1r   = (const float*)d_in[8];
    const float* g1    = (const float*)d_in[9];
    const float* be1   = (const float*)d_in[10];
    const float* W2l   = (const float*)d_in[11];
    const float* b2    = (const float*)d_in[12];
    const float* W2r   = (const float*)d_in[13];
    const float* g2    = (const float*)d_in[14];
    const float* be2   = (const float*)d_in[15];
    const float* Wlin  = (const float*)d_in[16];
    const float* blin  = (const float*)d_in[17];
    float* out = (float*)d_out;

    // workspace layout
    char* ws = (char*)d_ws;
    float* xbuf    = (float*)ws;                                  // N*HID
    float* hbuf    = xbuf + (size_t)N_NODES * HID;                // N*HID
    int*   deg     = (int*)(hbuf + (size_t)N_NODES * HID);        // N
    int*   row_ptr = deg + N_NODES;                               // N+1
    int*   cursor  = row_ptr + N_NODES + 1;                       // N
    int*   csr_src = cursor + N_NODES;                            // E
    int*   blockSums = csr_src + N_EDGES;                         // SCAN_B
    int*   blockOff  = blockSums + SCAN_B;                        // SCAN_B
    float* sums    = (float*)(blockOff + SCAN_B);                 // HID
    float* sumsq   = sums + HID;                                  // HID
    float* scale   = sumsq + HID;                                 // HID
    float* shift   = scale + HID;                                 // HID
    float* graph_x = shift + HID;                                 // NGRAPH*HID

    // ---- embed ----
    k_embed<<<(N_NODES * 16 + 255) / 256, 256, 0, stream>>>(sid, cid, sW, cW, xbuf);

    // ---- CSR build (reused by both layers) ----
    hipMemsetAsync(deg, 0, N_NODES * sizeof(int), stream);
    k_hist<<<(N_EDGES + 255) / 256, 256, 0, stream>>>(edst, deg);
    k_scan_part<<<SCAN_B, SCAN_T, 0, stream>>>(deg, row_ptr, blockSums);
    k_scan_mid<<<1, 128, 0, stream>>>(blockSums, blockOff, row_ptr);
    k_scan_add<<<SCAN_B, SCAN_T, 0, stream>>>(row_ptr, blockOff, cursor);
    k_scatter<<<(N_EDGES + 255) / 256, 256, 0, stream>>>(esrc, edst, cursor, csr_src);

    // ---- layer 1 ----
    hipMemsetAsync(sums, 0, 2 * HID * sizeof(float), stream);
    k_sage_fused<<<768, 256, 0, stream>>>(xbuf, row_ptr, csr_src, W1l, b1, W1r,
                                          hbuf, sums, sumsq);
    k_bn_params<<<1, 64, 0, stream>>>(sums, sumsq, g1, be1, scale, shift);
    k_bn_relu<<<(N_NODES * 16 + 255) / 256, 256, 0, stream>>>(hbuf, scale, shift, xbuf);

    // ---- layer 2 ----
    hipMemsetAsync(sums, 0, 2 * HID * sizeof(float), stream);
    k_sage_fused<<<768, 256, 0, stream>>>(xbuf, row_ptr, csr_src, W2l, b2, W2r,
                                          hbuf, sums, sumsq);
    k_bn_params<<<1, 64, 0, stream>>>(sums, sumsq, g2, be2, scale, shift);
    k_bn_relu<<<(N_NODES * 16 + 255) / 256, 256, 0, stream>>>(hbuf, scale, shift, xbuf);

    // ---- pool + classifier ----
    hipMemsetAsync(graph_x, 0, (size_t)NGRAPH * HID * sizeof(float), stream);
    k_pool<<<1024, 64, 0, stream>>>(xbuf, batch, graph_x);
    k_cls<<<(NGRAPH * NCLS + 255) / 256, 256, 0, stream>>>(graph_x, Wlin, blin, out);
}

// Round 4
// 470.127 us; speedup vs baseline: 5.0980x; 1.0748x over previous
//
#include <hip/hip_runtime.h>

#define N_NODES 100000
#define N_EDGES 1200000
#define HID 64
#define NGRAPH 512
#define NCLS 2
#define BN_EPS 1e-5f
#define WPAD 68   // transposed-weight row stride

#define SCAN_B 98          // ceil(100000/1024)
#define SCAN_T 1024

#define SAGE_T 512         // 8 waves/block share one weight copy
#define SAGE_W (SAGE_T/64)

// ---------------- embedding ----------------
__global__ void k_embed(const int* __restrict__ sid, const int* __restrict__ cid,
                        const float* __restrict__ sW, const float* __restrict__ cW,
                        float* __restrict__ x) {
    int idx = blockIdx.x * blockDim.x + threadIdx.x;   // over N*16
    if (idx >= N_NODES * 16) return;
    int i = idx >> 4, q = idx & 15;
    float4 s = *(const float4*)&sW[sid[i] * HID + q * 4];
    float4 c = *(const float4*)&cW[cid[i] * HID + q * 4];
    *(float4*)&x[i * HID + q * 4] = make_float4(s.x + c.x, s.y + c.y, s.z + c.z, s.w + c.w);
}

// ---------------- CSR build ----------------
__global__ void k_hist(const int* __restrict__ dst, int* __restrict__ deg) {
    int e = blockIdx.x * blockDim.x + threadIdx.x;
    if (e < N_EDGES) atomicAdd(&deg[dst[e]], 1);
}

__global__ __launch_bounds__(SCAN_T) void k_scan_part(const int* __restrict__ deg,
                                                      int* __restrict__ row_ptr,
                                                      int* __restrict__ blockSums) {
    __shared__ int sh[SCAN_T];
    int t = threadIdx.x;
    int i = blockIdx.x * SCAN_T + t;
    int v = (i < N_NODES) ? deg[i] : 0;
    sh[t] = v;
    __syncthreads();
    #pragma unroll
    for (int off = 1; off < SCAN_T; off <<= 1) {
        int cur = sh[t];
        int u = (t >= off) ? sh[t - off] : 0;
        __syncthreads();
        sh[t] = cur + u;
        __syncthreads();
    }
    if (i < N_NODES) row_ptr[i] = sh[t] - v;
    if (t == SCAN_T - 1) blockSums[blockIdx.x] = sh[t];
}

__global__ __launch_bounds__(128) void k_scan_mid(int* __restrict__ blockSums,
                                                  int* __restrict__ blockOff,
                                                  int* __restrict__ row_ptr) {
    __shared__ int sh[128];
    int t = threadIdx.x;
    int v = (t < SCAN_B) ? blockSums[t] : 0;
    sh[t] = v;
    __syncthreads();
    #pragma unroll
    for (int off = 1; off < 128; off <<= 1) {
        int cur = sh[t];
        int u = (t >= off) ? sh[t - off] : 0;
        __syncthreads();
        sh[t] = cur + u;
        __syncthreads();
    }
    if (t < SCAN_B) blockOff[t] = sh[t] - v;
    if (t == 0) row_ptr[N_NODES] = N_EDGES;
}

__global__ __launch_bounds__(SCAN_T) void k_scan_add(int* __restrict__ row_ptr,
                                                     const int* __restrict__ blockOff,
                                                     int* __restrict__ cursor) {
    int i = blockIdx.x * SCAN_T + threadIdx.x;
    if (i >= N_NODES) return;
    int rp = row_ptr[i] + blockOff[blockIdx.x];
    row_ptr[i] = rp;
    cursor[i] = rp;
}

__global__ void k_scatter(const int* __restrict__ src, const int* __restrict__ dst,
                          int* __restrict__ cursor, int* __restrict__ csr_src) {
    int e = blockIdx.x * blockDim.x + threadIdx.x;
    if (e >= N_EDGES) return;
    int slot = atomicAdd(&cursor[dst[e]], 1);
    csr_src[slot] = src[e];
}

// ---------------- fused SAGE layer ----------------
// FUSE_BN: input is the previous layer's RAW pre-BN h; apply relu(h*sc+sh) on the
// fly per gathered/self element (lane d only needs scale[d], shift[d] in regs).
template<bool FUSE_BN>
__global__ __launch_bounds__(SAGE_T, 6) void k_sage_fused(
    const float* __restrict__ x, const int* __restrict__ row_ptr,
    const int* __restrict__ csr_src,
    const float* __restrict__ Wl, const float* __restrict__ bl,
    const float* __restrict__ Wr,
    const float* __restrict__ scale, const float* __restrict__ shift,
    float* __restrict__ h_out, float* __restrict__ sums, float* __restrict__ sumsq) {
    __shared__ float sWlT[HID * WPAD];           // [d][k], transposed, padded
    __shared__ float sWrT[HID * WPAD];
    __shared__ float smean[SAGE_W][4][HID];      // [wave][node][dim]
    __shared__ float sxr[SAGE_W][4][HID];
    int tid = threadIdx.x;
    for (int t = tid; t < HID * HID; t += SAGE_T) {
        int k = t >> 6, dd = t & 63;
        sWlT[dd * WPAD + k] = Wl[t];
        sWrT[dd * WPAD + k] = Wr[t];
    }
    __syncthreads();
    int wv = tid >> 6, d = tid & 63;
    float bias = bl[d];
    float sc = FUSE_BN ? scale[d] : 1.f;
    float sh = FUSE_BN ? shift[d] : 0.f;
    float accs = 0.f, accq = 0.f;
    const int quads = N_NODES / 4;               // 25000, exact
    for (int q = blockIdx.x * SAGE_W + wv; q < quads; q += gridDim.x * SAGE_W) {
        int base = q * 4;
        float hv[4];
        #pragma unroll
        for (int n = 0; n < 4; ++n) {
            int i = base + n;
            int beg = row_ptr[i], end = row_ptr[i + 1];
            float m0 = 0.f, m1 = 0.f, m2 = 0.f, m3 = 0.f;
            int e = beg;
            for (; e + 4 <= end; e += 4) {       // 4 gathers in flight
                int s0 = csr_src[e], s1 = csr_src[e + 1];
                int s2 = csr_src[e + 2], s3 = csr_src[e + 3];
                float v0 = x[(size_t)s0 * HID + d];
                float v1 = x[(size_t)s1 * HID + d];
                float v2 = x[(size_t)s2 * HID + d];
                float v3 = x[(size_t)s3 * HID + d];
                if (FUSE_BN) {
                    v0 = fmaxf(fmaf(v0, sc, sh), 0.f);
                    v1 = fmaxf(fmaf(v1, sc, sh), 0.f);
                    v2 = fmaxf(fmaf(v2, sc, sh), 0.f);
                    v3 = fmaxf(fmaf(v3, sc, sh), 0.f);
                }
                m0 += v0; m1 += v1; m2 += v2; m3 += v3;
            }
            for (; e < end; ++e) {
                float v = x[(size_t)csr_src[e] * HID + d];
                if (FUSE_BN) v = fmaxf(fmaf(v, sc, sh), 0.f);
                m0 += v;
            }
            int deg = end - beg;
            smean[wv][n][d] = ((m0 + m1) + (m2 + m3)) / (float)max(deg, 1);
            float xv = x[(size_t)i * HID + d];
            if (FUSE_BN) xv = fmaxf(fmaf(xv, sc, sh), 0.f);
            sxr[wv][n][d] = xv;
            hv[n] = bias;
        }
        // wave-private LDS: producer==consumer wave, no block barrier needed
        #pragma unroll
        for (int kq = 0; kq < 16; ++kq) {
            float4 wl = *(const float4*)&sWlT[d * WPAD + kq * 4];
            float4 wr = *(const float4*)&sWrT[d * WPAD + kq * 4];
            #pragma unroll
            for (int n = 0; n < 4; ++n) {
                float4 mm = *(const float4*)&smean[wv][n][kq * 4];
                float4 xx = *(const float4*)&sxr[wv][n][kq * 4];
                hv[n] += mm.x * wl.x + mm.y * wl.y + mm.z * wl.z + mm.w * wl.w
                       + xx.x * wr.x + xx.y * wr.y + xx.z * wr.z + xx.w * wr.w;
            }
        }
        #pragma unroll
        for (int n = 0; n < 4; ++n) {
            h_out[(size_t)(base + n) * HID + d] = hv[n];
            accs += hv[n];
            accq += hv[n] * hv[n];
        }
    }
    __syncthreads();
    smean[wv][0][d] = accs;
    sxr[wv][0][d]   = accq;
    __syncthreads();
    if (wv == 0) {
        float s = 0.f, qq = 0.f;
        #pragma unroll
        for (int w = 0; w < SAGE_W; ++w) { s += smean[w][0][d]; qq += sxr[w][0][d]; }
        atomicAdd(&sums[d], s);
        atomicAdd(&sumsq[d], qq);
    }
}

// ---------------- BN params ----------------
__global__ void k_bn_params(const float* __restrict__ sums, const float* __restrict__ sumsq,
                            const float* __restrict__ g, const float* __restrict__ be,
                            float* __restrict__ scale, float* __restrict__ shift) {
    int d = threadIdx.x;
    if (d >= HID) return;
    float mu  = sums[d] * (1.f / N_NODES);
    float var = sumsq[d] * (1.f / N_NODES) - mu * mu;
    float sc  = g[d] * rsqrtf(var + BN_EPS);
    scale[d] = sc;
    shift[d] = be[d] - mu * sc;
}

// ---------------- pool (fused bn2+relu) + classifier ----------------
__global__ void k_pool(const float* __restrict__ h, const int* __restrict__ batch,
                       const float* __restrict__ scale, const float* __restrict__ shift,
                       float* __restrict__ graph_x) {
    int d = threadIdx.x;   // 64 threads
    float sc = scale[d], sh = shift[d];
    int chunk = (N_NODES + gridDim.x - 1) / gridDim.x;
    int a = blockIdx.x * chunk;
    int b = min(a + chunk, N_NODES);
    if (a >= b) return;
    int cur = batch[a];
    float acc = 0.f;
    for (int i = a; i < b; ++i) {
        int g = batch[i];
        if (g != cur) {
            atomicAdd(&graph_x[cur * HID + d], acc);
            acc = 0.f;
            cur = g;
        }
        acc += fmaxf(fmaf(h[(size_t)i * HID + d], sc, sh), 0.f);
    }
    atomicAdd(&graph_x[cur * HID + d], acc);
}

__global__ void k_cls(const float* __restrict__ graph_x, const float* __restrict__ Wlin,
                      const float* __restrict__ blin, float* __restrict__ out) {
    int idx = blockIdx.x * blockDim.x + threadIdx.x;
    if (idx >= NGRAPH * NCLS) return;
    int g = idx / NCLS, c = idx % NCLS;
    float acc = blin[c];
    #pragma unroll
    for (int k = 0; k < HID; ++k) acc += graph_x[g * HID + k] * Wlin[k * NCLS + c];
    out[idx] = acc;
}

// ---------------- launch ----------------
extern "C" void kernel_launch(void* const* d_in, const int* in_sizes, int n_in,
                              void* d_out, int out_size, void* d_ws, size_t ws_size,
                              hipStream_t stream) {
    const int*   sid   = (const int*)d_in[0];
    const int*   cid   = (const int*)d_in[1];
    const int*   esrc  = (const int*)d_in[2];
    const int*   edst  = esrc + N_EDGES;
    const int*   batch = (const int*)d_in[3];
    const float* sW    = (const float*)d_in[4];
    const float* cW    = (const float*)d_in[5];
    const float* W1l   = (const float*)d_in[6];
    const float* b1    = (const float*)d_in[7];
    const float* W1r   = (const float*)d_in[8];
    const float* g1    = (const float*)d_in[9];
    const float* be1   = (const float*)d_in[10];
    const float* W2l   = (const float*)d_in[11];
    const float* b2    = (const float*)d_in[12];
    const float* W2r   = (const float*)d_in[13];
    const float* g2    = (const float*)d_in[14];
    const float* be2   = (const float*)d_in[15];
    const float* Wlin  = (const float*)d_in[16];
    const float* blin  = (const float*)d_in[17];
    float* out = (float*)d_out;

    // workspace layout
    char* ws = (char*)d_ws;
    float* xbuf    = (float*)ws;                                  // N*HID  (x0 = embed)
    float* hbuf    = xbuf + (size_t)N_NODES * HID;                // N*HID  (h1 raw, then reused)
    float* hbuf2   = hbuf + (size_t)N_NODES * HID;                // N*HID  (h2 raw)
    int*   deg     = (int*)(hbuf2 + (size_t)N_NODES * HID);       // N
    int*   row_ptr = deg + N_NODES;                               // N+1
    int*   cursor  = row_ptr + N_NODES + 1;                       // N
    int*   csr_src = cursor + N_NODES;                            // E
    int*   blockSums = csr_src + N_EDGES;                         // SCAN_B
    int*   blockOff  = blockSums + SCAN_B;                        // SCAN_B
    float* sums    = (float*)(blockOff + SCAN_B);                 // HID
    float* sumsq   = sums + HID;                                  // HID
    float* scale1  = sumsq + HID;                                 // HID
    float* shift1  = scale1 + HID;                                // HID
    float* scale2  = shift1 + HID;                                // HID
    float* shift2  = scale2 + HID;                                // HID
    float* graph_x = shift2 + HID;                                // NGRAPH*HID

    // ---- embed ----
    k_embed<<<(N_NODES * 16 + 255) / 256, 256, 0, stream>>>(sid, cid, sW, cW, xbuf);

    // ---- CSR build (reused by both layers) ----
    hipMemsetAsync(deg, 0, N_NODES * sizeof(int), stream);
    k_hist<<<(N_EDGES + 255) / 256, 256, 0, stream>>>(edst, deg);
    k_scan_part<<<SCAN_B, SCAN_T, 0, stream>>>(deg, row_ptr, blockSums);
    k_scan_mid<<<1, 128, 0, stream>>>(blockSums, blockOff, row_ptr);
    k_scan_add<<<SCAN_B, SCAN_T, 0, stream>>>(row_ptr, blockOff, cursor);
    k_scatter<<<(N_EDGES + 255) / 256, 256, 0, stream>>>(esrc, edst, cursor, csr_src);

    // ---- layer 1: x0 -> h1 (raw) + stats ----
    hipMemsetAsync(sums, 0, 2 * HID * sizeof(float), stream);
    k_sage_fused<false><<<768, SAGE_T, 0, stream>>>(xbuf, row_ptr, csr_src,
                                                    W1l, b1, W1r, nullptr, nullptr,
                                                    hbuf, sums, sumsq);
    k_bn_params<<<1, 64, 0, stream>>>(sums, sumsq, g1, be1, scale1, shift1);

    // ---- layer 2: relu(bn1(h1)) on the fly -> h2 (raw) + stats ----
    hipMemsetAsync(sums, 0, 2 * HID * sizeof(float), stream);
    k_sage_fused<true><<<768, SAGE_T, 0, stream>>>(hbuf, row_ptr, csr_src,
                                                   W2l, b2, W2r, scale1, shift1,
                                                   hbuf2, sums, sumsq);
    k_bn_params<<<1, 64, 0, stream>>>(sums, sumsq, g2, be2, scale2, shift2);

    // ---- pool (fused bn2+relu) + classifier ----
    hipMemsetAsync(graph_x, 0, (size_t)NGRAPH * HID * sizeof(float), stream);
    k_pool<<<1024, 64, 0, stream>>>(hbuf2, batch, scale2, shift2, graph_x);
    k_cls<<<(NGRAPH * NCLS + 255) / 256, 256, 0, stream>>>(graph_x, Wlin, blin, out);
}

// Round 5
// 415.346 us; speedup vs baseline: 5.7704x; 1.1319x over previous
//
#include <hip/hip_runtime.h>
#include <stdint.h>

#define N_NODES 100000
#define N_EDGES 1200000
#define HID 64
#define NGRAPH 512
#define NCLS 2
#define BN_EPS 1e-5f

#define SCAN_B 98          // ceil(100000/1024)
#define SCAN_T 1024
#define NTILES (N_NODES / 16)   // 6250, exact

typedef __attribute__((ext_vector_type(8))) short short8;   // 8 bf16 = 4 VGPRs
typedef __attribute__((ext_vector_type(4))) float f32x4;

__device__ inline float bf2f(uint32_t hi16) {              // hi16 in low bits
    uint32_t u = hi16 << 16;
    return __builtin_bit_cast(float, u);
}
__device__ inline uint32_t f2bf_rtn(float f) {             // round-to-nearest-even
    uint32_t u = __builtin_bit_cast(uint32_t, f);
    return (u + 0x7FFFu + ((u >> 16) & 1u)) >> 16;
}

// ---------------- embedding -> bf16 x ----------------
__global__ void k_embed(const int* __restrict__ sid, const int* __restrict__ cid,
                        const float* __restrict__ sW, const float* __restrict__ cW,
                        ushort* __restrict__ xb) {
    int t = blockIdx.x * blockDim.x + threadIdx.x;   // over N*16, 4 dims each
    if (t >= N_NODES * 16) return;
    int i = t >> 4, q = t & 15;
    float4 s = *(const float4*)&sW[(size_t)sid[i] * HID + q * 4];
    float4 c = *(const float4*)&cW[(size_t)cid[i] * HID + q * 4];
    uint2 o;
    o.x = f2bf_rtn(s.x + c.x) | (f2bf_rtn(s.y + c.y) << 16);
    o.y = f2bf_rtn(s.z + c.z) | (f2bf_rtn(s.w + c.w) << 16);
    *(uint2*)&xb[(size_t)t * 4] = o;
}

// ---------------- CSR build ----------------
__global__ void k_hist(const int* __restrict__ dst, int* __restrict__ deg) {
    int e = blockIdx.x * blockDim.x + threadIdx.x;
    if (e < N_EDGES) atomicAdd(&deg[dst[e]], 1);
}

__global__ __launch_bounds__(SCAN_T) void k_scan_part(const int* __restrict__ deg,
                                                      int* __restrict__ row_ptr,
                                                      int* __restrict__ blockSums) {
    __shared__ int sh[SCAN_T];
    int t = threadIdx.x;
    int i = blockIdx.x * SCAN_T + t;
    int v = (i < N_NODES) ? deg[i] : 0;
    sh[t] = v;
    __syncthreads();
    #pragma unroll
    for (int off = 1; off < SCAN_T; off <<= 1) {
        int cur = sh[t];
        int u = (t >= off) ? sh[t - off] : 0;
        __syncthreads();
        sh[t] = cur + u;
        __syncthreads();
    }
    if (i < N_NODES) row_ptr[i] = sh[t] - v;
    if (t == SCAN_T - 1) blockSums[blockIdx.x] = sh[t];
}

__global__ __launch_bounds__(128) void k_scan_mid(int* __restrict__ blockSums,
                                                  int* __restrict__ blockOff,
                                                  int* __restrict__ row_ptr) {
    __shared__ int sh[128];
    int t = threadIdx.x;
    int v = (t < SCAN_B) ? blockSums[t] : 0;
    sh[t] = v;
    __syncthreads();
    #pragma unroll
    for (int off = 1; off < 128; off <<= 1) {
        int cur = sh[t];
        int u = (t >= off) ? sh[t - off] : 0;
        __syncthreads();
        sh[t] = cur + u;
        __syncthreads();
    }
    if (t < SCAN_B) blockOff[t] = sh[t] - v;
    if (t == 0) row_ptr[N_NODES] = N_EDGES;
}

__global__ __launch_bounds__(SCAN_T) void k_scan_add(int* __restrict__ row_ptr,
                                                     const int* __restrict__ blockOff,
                                                     int* __restrict__ cursor) {
    int i = blockIdx.x * SCAN_T + threadIdx.x;
    if (i >= N_NODES) return;
    int rp = row_ptr[i] + blockOff[blockIdx.x];
    row_ptr[i] = rp;
    cursor[i] = rp;
}

__global__ void k_scatter(const int* __restrict__ src, const int* __restrict__ dst,
                          int* __restrict__ cursor, int* __restrict__ csr_src) {
    int e = blockIdx.x * blockDim.x + threadIdx.x;
    if (e >= N_EDGES) return;
    int slot = atomicAdd(&cursor[dst[e]], 1);
    csr_src[slot] = src[e];
}

// ---------------- pack both layers' weights into MFMA B-fragments (bf16) ----------------
// B-frag layout for mfma_f32_16x16x32_bf16: lane l holds B[k=(l>>4)*8+j][n=l&15].
// Wcomb[128][64]: rows 0..63 = Wl (k-dim of mean), 64..127 = Wr (k-dim of self).
__global__ void k_wpack(const float* __restrict__ W1l, const float* __restrict__ W1r,
                        const float* __restrict__ W2l, const float* __restrict__ W2r,
                        ushort* __restrict__ wpk1, ushort* __restrict__ wpk2) {
    int gid = blockIdx.x * blockDim.x + threadIdx.x;   // 2048 threads
    if (gid >= 2048) return;
    int L = gid >> 10;
    int r = gid & 1023;
    int tile = r >> 6;         // 0..15 = nt*4+kt
    int lane = r & 63;
    int nt = tile >> 2, kt = tile & 3;
    const float* WL = L ? W2l : W1l;
    const float* WR = L ? W2r : W1r;
    ushort* dstp = L ? wpk2 : wpk1;
    #pragma unroll
    for (int j = 0; j < 8; ++j) {
        int k = kt * 32 + (lane >> 4) * 8 + j;
        int n = nt * 16 + (lane & 15);
        float v = (k < 64) ? WL[k * HID + n] : WR[(k - 64) * HID + n];
        dstp[(size_t)(tile * 64 + lane) * 8 + j] = (ushort)f2bf_rtn(v);
    }
}

// ---------------- gather-mean (bf16 in -> bf16 mean out) ----------------
// One wave per node. 4 lane-groups of 16 handle 4 edges concurrently; each
// lane loads uint2 (4 bf16 dims) -> 512B in flight per iteration per wave.
__global__ __launch_bounds__(256) void k_gather(const ushort* __restrict__ xb,
                                                const int* __restrict__ row_ptr,
                                                const int* __restrict__ csr_src,
                                                ushort* __restrict__ meanb) {
    int lane = threadIdx.x & 63;
    int wv = threadIdx.x >> 6;
    int g = lane >> 4;          // edge group 0..3
    int cc = lane & 15;         // uint2 slot -> dims 4cc..4cc+3
    const uint2* xb2 = (const uint2*)xb;
    uint2* mb2 = (uint2*)meanb;
    for (int node = blockIdx.x * 4 + wv; node < N_NODES; node += gridDim.x * 4) {
        int beg = row_ptr[node], end = row_ptr[node + 1];
        int deg = end - beg;
        float a0 = 0.f, a1 = 0.f, a2 = 0.f, a3 = 0.f;
        int iters = (deg + 3) >> 2;
        for (int it = 0; it < iters; ++it) {
            int e = beg + it * 4 + g;
            if (e < end) {
                int s = csr_src[e];
                uint2 u = xb2[(size_t)s * 16 + cc];
                a0 += bf2f(u.x & 0xFFFFu);
                a1 += bf2f(u.x >> 16);
                a2 += bf2f(u.y & 0xFFFFu);
                a3 += bf2f(u.y >> 16);
            }
        }
        // combine the 4 edge-groups (lanes {l, l^16, l^32, l^48})
        a0 += __shfl_xor(a0, 16); a0 += __shfl_xor(a0, 32);
        a1 += __shfl_xor(a1, 16); a1 += __shfl_xor(a1, 32);
        a2 += __shfl_xor(a2, 16); a2 += __shfl_xor(a2, 32);
        a3 += __shfl_xor(a3, 16); a3 += __shfl_xor(a3, 32);
        float inv = 1.f / (float)max(deg, 1);
        if (lane < 16) {
            uint2 o;
            o.x = f2bf_rtn(a0 * inv) | (f2bf_rtn(a1 * inv) << 16);
            o.y = f2bf_rtn(a2 * inv) | (f2bf_rtn(a3 * inv) << 16);
            mb2[(size_t)node * 16 + cc] = o;
        }
    }
}

// ---------------- MFMA linear: h = [mean|self] @ [Wl;Wr] + b, + BN stats ----------------
// Per wave: 16-node tile. A from global (bf16), B-frags in registers, no LDS.
__global__ __launch_bounds__(256) void k_gemm(const ushort* __restrict__ meanb,
                                              const ushort* __restrict__ selfb,
                                              const ushort* __restrict__ wpk,
                                              const float* __restrict__ bias,
                                              ushort* __restrict__ hout,
                                              float* __restrict__ sums,
                                              float* __restrict__ sumsq) {
    int lane = threadIdx.x & 63;
    int wv = threadIdx.x >> 6;
    int r16 = lane & 15;        // A row / C col within tile
    int grp = lane >> 4;
    short8 bfrag[4][4];
    const short8* wp = (const short8*)wpk;
    #pragma unroll
    for (int nt = 0; nt < 4; ++nt)
        #pragma unroll
        for (int kt = 0; kt < 4; ++kt)
            bfrag[nt][kt] = wp[(nt * 4 + kt) * 64 + lane];
    float bcol[4];
    #pragma unroll
    for (int nt = 0; nt < 4; ++nt) bcol[nt] = bias[nt * 16 + r16];
    float sv[4] = {0.f, 0.f, 0.f, 0.f}, qv[4] = {0.f, 0.f, 0.f, 0.f};

    for (int tile = blockIdx.x * 4 + wv; tile < NTILES; tile += gridDim.x * 4) {
        int node = tile * 16 + r16;
        const short8* mrow = (const short8*)(meanb + (size_t)node * HID);
        const short8* srow = (const short8*)(selfb + (size_t)node * HID);
        short8 a[4];
        a[0] = mrow[grp];       // k  0..31
        a[1] = mrow[4 + grp];   // k 32..63
        a[2] = srow[grp];       // k 64..95
        a[3] = srow[4 + grp];   // k 96..127
        f32x4 acc[4];
        #pragma unroll
        for (int nt = 0; nt < 4; ++nt) acc[nt] = (f32x4){0.f, 0.f, 0.f, 0.f};
        #pragma unroll
        for (int nt = 0; nt < 4; ++nt)
            #pragma unroll
            for (int kt = 0; kt < 4; ++kt)
                acc[nt] = __builtin_amdgcn_mfma_f32_16x16x32_bf16(a[kt], bfrag[nt][kt],
                                                                  acc[nt], 0, 0, 0);
        // epilogue: bias, bf16 store, BN stats. C: col=lane&15, row=(lane>>4)*4+r
        #pragma unroll
        for (int nt = 0; nt < 4; ++nt) {
            #pragma unroll
            for (int r = 0; r < 4; ++r) {
                float hv = acc[nt][r] + bcol[nt];
                int rrow = tile * 16 + grp * 4 + r;
                hout[(size_t)rrow * HID + nt * 16 + r16] = (ushort)f2bf_rtn(hv);
                sv[nt] += hv;
                qv[nt] += hv * hv;
            }
        }
    }
    #pragma unroll
    for (int nt = 0; nt < 4; ++nt) {
        float v = sv[nt];
        v += __shfl_xor(v, 16); v += __shfl_xor(v, 32);
        float q = qv[nt];
        q += __shfl_xor(q, 16); q += __shfl_xor(q, 32);
        if (grp == 0) {
            atomicAdd(&sums[nt * 16 + r16], v);
            atomicAdd(&sumsq[nt * 16 + r16], q);
        }
    }
}

// ---------------- BN params ----------------
__global__ void k_bn_params(const float* __restrict__ sums, const float* __restrict__ sumsq,
                            const float* __restrict__ g, const float* __restrict__ be,
                            float* __restrict__ scale, float* __restrict__ shift) {
    int d = threadIdx.x;
    if (d >= HID) return;
    float mu  = sums[d] * (1.f / N_NODES);
    float var = sumsq[d] * (1.f / N_NODES) - mu * mu;
    float sc  = g[d] * rsqrtf(var + BN_EPS);
    scale[d] = sc;
    shift[d] = be[d] - mu * sc;
}

// ---------------- act: relu(h*sc+sh), bf16 -> bf16 ----------------
__global__ void k_act(const ushort* __restrict__ h, const float* __restrict__ scale,
                      const float* __restrict__ shift, ushort* __restrict__ act) {
    int t = blockIdx.x * blockDim.x + threadIdx.x;   // over N*16, 4 dims each
    if (t >= N_NODES * 16) return;
    int q = t & 15;
    uint2 u = *(const uint2*)&h[(size_t)t * 4];
    float4 sc = *(const float4*)&scale[q * 4];
    float4 sh = *(const float4*)&shift[q * 4];
    float f0 = fmaxf(fmaf(bf2f(u.x & 0xFFFFu), sc.x, sh.x), 0.f);
    float f1 = fmaxf(fmaf(bf2f(u.x >> 16),     sc.y, sh.y), 0.f);
    float f2 = fmaxf(fmaf(bf2f(u.y & 0xFFFFu), sc.z, sh.z), 0.f);
    float f3 = fmaxf(fmaf(bf2f(u.y >> 16),     sc.w, sh.w), 0.f);
    uint2 o;
    o.x = f2bf_rtn(f0) | (f2bf_rtn(f1) << 16);
    o.y = f2bf_rtn(f2) | (f2bf_rtn(f3) << 16);
    *(uint2*)&act[(size_t)t * 4] = o;
}

// ---------------- pool (fused bn2+relu, bf16 in) + classifier ----------------
__global__ void k_pool(const ushort* __restrict__ h, const int* __restrict__ batch,
                       const float* __restrict__ scale, const float* __restrict__ shift,
                       float* __restrict__ graph_x) {
    int d = threadIdx.x;   // 64 threads
    float sc = scale[d], sh = shift[d];
    int chunk = (N_NODES + gridDim.x - 1) / gridDim.x;
    int a = blockIdx.x * chunk;
    int b = min(a + chunk, N_NODES);
    if (a >= b) return;
    int cur = batch[a];
    float acc = 0.f;
    for (int i = a; i < b; ++i) {
        int g = batch[i];
        if (g != cur) {
            atomicAdd(&graph_x[cur * HID + d], acc);
            acc = 0.f;
            cur = g;
        }
        float v = bf2f((uint32_t)h[(size_t)i * HID + d]);
        acc += fmaxf(fmaf(v, sc, sh), 0.f);
    }
    atomicAdd(&graph_x[cur * HID + d], acc);
}

__global__ void k_cls(const float* __restrict__ graph_x, const float* __restrict__ Wlin,
                      const float* __restrict__ blin, float* __restrict__ out) {
    int idx = blockIdx.x * blockDim.x + threadIdx.x;
    if (idx >= NGRAPH * NCLS) return;
    int g = idx / NCLS, c = idx % NCLS;
    float acc = blin[c];
    #pragma unroll
    for (int k = 0; k < HID; ++k) acc += graph_x[g * HID + k] * Wlin[k * NCLS + c];
    out[idx] = acc;
}

// ---------------- launch ----------------
extern "C" void kernel_launch(void* const* d_in, const int* in_sizes, int n_in,
                              void* d_out, int out_size, void* d_ws, size_t ws_size,
                              hipStream_t stream) {
    const int*   sid   = (const int*)d_in[0];
    const int*   cid   = (const int*)d_in[1];
    const int*   esrc  = (const int*)d_in[2];
    const int*   edst  = esrc + N_EDGES;
    const int*   batch = (const int*)d_in[3];
    const float* sW    = (const float*)d_in[4];
    const float* cW    = (const float*)d_in[5];
    const float* W1l   = (const float*)d_in[6];
    const float* b1    = (const float*)d_in[7];
    const float* W1r   = (const float*)d_in[8];
    const float* g1    = (const float*)d_in[9];
    const float* be1   = (const float*)d_in[10];
    const float* W2l   = (const float*)d_in[11];
    const float* b2    = (const float*)d_in[12];
    const float* W2r   = (const float*)d_in[13];
    const float* g2    = (const float*)d_in[14];
    const float* be2   = (const float*)d_in[15];
    const float* Wlin  = (const float*)d_in[16];
    const float* blin  = (const float*)d_in[17];
    float* out = (float*)d_out;

    // workspace layout (bf16 feature buffers first, all 16B-aligned)
    const size_t FEAT = (size_t)N_NODES * HID;       // elements
    ushort* xb    = (ushort*)d_ws;                   // x0, bf16
    ushort* meanb = xb + FEAT;                       // mean (reused per layer)
    ushort* h1b   = meanb + FEAT;                    // raw h1
    ushort* act1b = h1b + FEAT;                      // relu(bn1(h1))
    ushort* h2b   = act1b + FEAT;                    // raw h2
    ushort* wpk1  = h2b + FEAT;                      // 8192 bf16
    ushort* wpk2  = wpk1 + 8192;
    float* fp     = (float*)(wpk2 + 8192);
    float* sums1  = fp;            float* sumsq1 = sums1 + HID;
    float* sums2  = sumsq1 + HID;  float* sumsq2 = sums2 + HID;
    float* scale1 = sumsq2 + HID;  float* shift1 = scale1 + HID;
    float* scale2 = shift1 + HID;  float* shift2 = scale2 + HID;
    float* graph_x = shift2 + HID;                   // NGRAPH*HID
    int* deg      = (int*)(graph_x + (size_t)NGRAPH * HID);
    int* row_ptr  = deg + N_NODES;
    int* cursor   = row_ptr + N_NODES + 1;
    int* csr_src  = cursor + N_NODES;
    int* blockSums = csr_src + N_EDGES;
    int* blockOff  = blockSums + SCAN_B;

    // ---- zero the accumulated buffers once ----
    hipMemsetAsync(deg, 0, N_NODES * sizeof(int), stream);
    hipMemsetAsync(sums1, 0, 4 * HID * sizeof(float), stream);   // sums1/sumsq1/sums2/sumsq2
    hipMemsetAsync(graph_x, 0, (size_t)NGRAPH * HID * sizeof(float), stream);

    // ---- embed + weight pack ----
    k_embed<<<(N_NODES * 16 + 255) / 256, 256, 0, stream>>>(sid, cid, sW, cW, xb);
    k_wpack<<<2, 1024, 0, stream>>>(W1l, W1r, W2l, W2r, wpk1, wpk2);

    // ---- CSR build ----
    k_hist<<<(N_EDGES + 255) / 256, 256, 0, stream>>>(edst, deg);
    k_scan_part<<<SCAN_B, SCAN_T, 0, stream>>>(deg, row_ptr, blockSums);
    k_scan_mid<<<1, 128, 0, stream>>>(blockSums, blockOff, row_ptr);
    k_scan_add<<<SCAN_B, SCAN_T, 0, stream>>>(row_ptr, blockOff, cursor);
    k_scatter<<<(N_EDGES + 255) / 256, 256, 0, stream>>>(esrc, edst, cursor, csr_src);

    // ---- layer 1 ----
    k_gather<<<4096, 256, 0, stream>>>(xb, row_ptr, csr_src, meanb);
    k_gemm<<<512, 256, 0, stream>>>(meanb, xb, wpk1, b1, h1b, sums1, sumsq1);
    k_bn_params<<<1, 64, 0, stream>>>(sums1, sumsq1, g1, be1, scale1, shift1);
    k_act<<<(N_NODES * 16 + 255) / 256, 256, 0, stream>>>(h1b, scale1, shift1, act1b);

    // ---- layer 2 ----
    k_gather<<<4096, 256, 0, stream>>>(act1b, row_ptr, csr_src, meanb);
    k_gemm<<<512, 256, 0, stream>>>(meanb, act1b, wpk2, b2, h2b, sums2, sumsq2);
    k_bn_params<<<1, 64, 0, stream>>>(sums2, sumsq2, g2, be2, scale2, shift2);

    // ---- pool (fused bn2+relu) + classifier ----
    k_pool<<<1024, 64, 0, stream>>>(h2b, batch, scale2, shift2, graph_x);
    k_cls<<<(NGRAPH * NCLS + 255) / 256, 256, 0, stream>>>(graph_x, Wlin, blin, out);
}

// Round 6
// 336.418 us; speedup vs baseline: 7.1243x; 1.2346x over previous
//
#include <hip/hip_runtime.h>
#include <stdint.h>

#define N_NODES 100000
#define N_EDGES 1200000
#define HID 64
#define NGRAPH 512
#define NCLS 2
#define BN_EPS 1e-5f

#define NTILES (N_NODES / 16)     // 6250, exact

// bucket sort: 1024-node buckets
#define BKT_SH 10
#define BKT_NODES 1024
#define NB 98                      // ceil(100000/1024)
#define EB_PER_BLK 4096            // edges per k_bucket block (256 thr x 16)
#define NBLK_E 293                 // ceil(1200000/4096)

typedef __attribute__((ext_vector_type(8))) short short8;   // 8 bf16 = 4 VGPRs
typedef __attribute__((ext_vector_type(4))) float f32x4;

__device__ inline float bf2f(uint32_t hi16) {
    uint32_t u = hi16 << 16;
    return __builtin_bit_cast(float, u);
}
__device__ inline uint32_t f2bf_rtn(float f) {             // round-to-nearest-even
    uint32_t u = __builtin_bit_cast(uint32_t, f);
    return (u + 0x7FFFu + ((u >> 16) & 1u)) >> 16;
}

// ---------------- embedding -> bf16 x ----------------
__global__ void k_embed(const int* __restrict__ sid, const int* __restrict__ cid,
                        const float* __restrict__ sW, const float* __restrict__ cW,
                        ushort* __restrict__ xb) {
    int t = blockIdx.x * blockDim.x + threadIdx.x;   // over N*16, 4 dims each
    if (t >= N_NODES * 16) return;
    int i = t >> 4, q = t & 15;
    float4 s = *(const float4*)&sW[(size_t)sid[i] * HID + q * 4];
    float4 c = *(const float4*)&cW[(size_t)cid[i] * HID + q * 4];
    uint2 o;
    o.x = f2bf_rtn(s.x + c.x) | (f2bf_rtn(s.y + c.y) << 16);
    o.y = f2bf_rtn(s.z + c.z) | (f2bf_rtn(s.w + c.w) << 16);
    *(uint2*)&xb[(size_t)t * 4] = o;
}

// ---------------- bucket CSR build ----------------
// 1) 98-bin histogram, LDS-aggregated
__global__ __launch_bounds__(256) void k_bhist(const int* __restrict__ dst,
                                               int* __restrict__ bhist) {
    __shared__ int h[NB];
    int tid = threadIdx.x;
    if (tid < NB) h[tid] = 0;
    __syncthreads();
    int base = blockIdx.x * EB_PER_BLK;
    #pragma unroll
    for (int i = 0; i < 16; ++i) {
        int e = base + i * 256 + tid;
        if (e < N_EDGES) atomicAdd(&h[dst[e] >> BKT_SH], 1);
    }
    __syncthreads();
    if (tid < NB) atomicAdd(&bhist[tid], h[tid]);
}

// 2) scan 98 totals -> bucket_off[0..98], init bucket_cursor
__global__ __launch_bounds__(128) void k_bscan(const int* __restrict__ bhist,
                                               int* __restrict__ bucket_off,
                                               int* __restrict__ bucket_cursor,
                                               int* __restrict__ row_ptr) {
    __shared__ int sh[128];
    int t = threadIdx.x;
    int v = (t < NB) ? bhist[t] : 0;
    sh[t] = v;
    __syncthreads();
    #pragma unroll
    for (int off = 1; off < 128; off <<= 1) {
        int cur = sh[t];
        int u = (t >= off) ? sh[t - off] : 0;
        __syncthreads();
        sh[t] = cur + u;
        __syncthreads();
    }
    if (t < NB) {
        int ex = sh[t] - v;
        bucket_off[t] = ex;
        bucket_cursor[t] = ex;
    }
    if (t == 0) {
        bucket_off[NB] = N_EDGES;
        row_ptr[N_NODES] = N_EDGES;
    }
}

// 3) scatter edges into bucket-grouped staging with per-block contiguous runs.
//    pk = (src << 10) | (dst & 1023)
__global__ __launch_bounds__(256) void k_bucket(const int* __restrict__ src,
                                                const int* __restrict__ dst,
                                                int* __restrict__ bucket_cursor,
                                                uint32_t* __restrict__ staged) {
    __shared__ int h[NB];
    __shared__ int cur[NB];
    int tid = threadIdx.x;
    if (tid < NB) h[tid] = 0;
    __syncthreads();
    uint32_t pk[16];
    int bk[16];
    int base = blockIdx.x * EB_PER_BLK;
    #pragma unroll
    for (int i = 0; i < 16; ++i) {
        int e = base + i * 256 + tid;
        if (e < N_EDGES) {
            int s = src[e], d = dst[e];
            bk[i] = d >> BKT_SH;
            pk[i] = ((uint32_t)s << BKT_SH) | (uint32_t)(d & (BKT_NODES - 1));
            atomicAdd(&h[bk[i]], 1);
        } else {
            bk[i] = -1;
        }
    }
    __syncthreads();
    if (tid < NB) cur[tid] = atomicAdd(&bucket_cursor[tid], h[tid]);
    __syncthreads();
    #pragma unroll
    for (int i = 0; i < 16; ++i) {
        if (bk[i] >= 0) {
            int slot = atomicAdd(&cur[bk[i]], 1);
            staged[slot] = pk[i];
        }
    }
}

// 4) per-bucket: node hist -> LDS scan -> row_ptr (coalesced) + place csr_src
__global__ __launch_bounds__(256) void k_place(const uint32_t* __restrict__ staged,
                                               const int* __restrict__ bucket_off,
                                               int* __restrict__ row_ptr,
                                               int* __restrict__ csr_src) {
    __shared__ int hist[BKT_NODES];
    __shared__ int cursor[BKT_NODES];
    __shared__ int part[256];
    int b = blockIdx.x;
    int tid = threadIdx.x;
    int nodes0 = b << BKT_SH;
    int nn = min(BKT_NODES, N_NODES - nodes0);
    int ebeg = bucket_off[b], eend = bucket_off[b + 1];
    #pragma unroll
    for (int j = 0; j < 4; ++j) hist[tid * 4 + j] = 0;
    __syncthreads();
    for (int e = ebeg + tid; e < eend; e += 256)
        atomicAdd(&hist[staged[e] & (BKT_NODES - 1)], 1);
    __syncthreads();
    // exclusive scan over 1024 node counts: 4 per thread + HS over 256 partials
    int c0 = hist[tid * 4 + 0], c1 = hist[tid * 4 + 1];
    int c2 = hist[tid * 4 + 2], c3 = hist[tid * 4 + 3];
    int s = c0 + c1 + c2 + c3;
    part[tid] = s;
    __syncthreads();
    #pragma unroll
    for (int off = 1; off < 256; off <<= 1) {
        int curv = part[tid];
        int u = (tid >= off) ? part[tid - off] : 0;
        __syncthreads();
        part[tid] = curv + u;
        __syncthreads();
    }
    int basev = ebeg + part[tid] - s;   // global exclusive base for node tid*4
    int e0 = basev, e1 = e0 + c0, e2 = e1 + c1, e3 = e2 + c2;
    cursor[tid * 4 + 0] = e0; cursor[tid * 4 + 1] = e1;
    cursor[tid * 4 + 2] = e2; cursor[tid * 4 + 3] = e3;
    #pragma unroll
    for (int j = 0; j < 4; ++j) {
        int i = tid * 4 + j;
        if (i < nn) row_ptr[nodes0 + i] = cursor[i];
    }
    __syncthreads();
    for (int e = ebeg + tid; e < eend; e += 256) {
        uint32_t pk = staged[e];
        int slot = atomicAdd(&cursor[pk & (BKT_NODES - 1)], 1);
        csr_src[slot] = (int)(pk >> BKT_SH);
    }
}

// ---------------- pack both layers' weights into MFMA B-fragments (bf16) ----------------
__global__ void k_wpack(const float* __restrict__ W1l, const float* __restrict__ W1r,
                        const float* __restrict__ W2l, const float* __restrict__ W2r,
                        ushort* __restrict__ wpk1, ushort* __restrict__ wpk2) {
    int gid = blockIdx.x * blockDim.x + threadIdx.x;   // 2048 threads
    if (gid >= 2048) return;
    int L = gid >> 10;
    int r = gid & 1023;
    int tile = r >> 6;         // 0..15 = nt*4+kt
    int lane = r & 63;
    int nt = tile >> 2, kt = tile & 3;
    const float* WL = L ? W2l : W1l;
    const float* WR = L ? W2r : W1r;
    ushort* dstp = L ? wpk2 : wpk1;
    #pragma unroll
    for (int j = 0; j < 8; ++j) {
        int k = kt * 32 + (lane >> 4) * 8 + j;
        int n = nt * 16 + (lane & 15);
        float v = (k < 64) ? WL[k * HID + n] : WR[(k - 64) * HID + n];
        dstp[(size_t)(tile * 64 + lane) * 8 + j] = (ushort)f2bf_rtn(v);
    }
}

// ---------------- gather-mean (bf16 in -> bf16 mean out) ----------------
// One wave per node; 4 lane-groups of 16 handle 4 edges; unroll x2 -> 8 rows in flight.
__global__ __launch_bounds__(256) void k_gather(const ushort* __restrict__ xb,
                                                const int* __restrict__ row_ptr,
                                                const int* __restrict__ csr_src,
                                                ushort* __restrict__ meanb) {
    int lane = threadIdx.x & 63;
    int wv = threadIdx.x >> 6;
    int g = lane >> 4;          // edge group 0..3
    int cc = lane & 15;         // uint2 slot -> dims 4cc..4cc+3
    const uint2* xb2 = (const uint2*)xb;
    uint2* mb2 = (uint2*)meanb;
    for (int node = blockIdx.x * 4 + wv; node < N_NODES; node += gridDim.x * 4) {
        int beg = row_ptr[node], end = row_ptr[node + 1];
        int deg = end - beg;
        float a0 = 0.f, a1 = 0.f, a2 = 0.f, a3 = 0.f;
        float b0 = 0.f, b1 = 0.f, b2 = 0.f, b3 = 0.f;
        int iters = (deg + 7) >> 3;
        for (int it = 0; it < iters; ++it) {
            int ea = beg + it * 8 + g;
            int eb = ea + 4;
            if (ea < end) {
                int s = csr_src[ea];
                uint2 u = xb2[(size_t)s * 16 + cc];
                a0 += bf2f(u.x & 0xFFFFu);
                a1 += bf2f(u.x >> 16);
                a2 += bf2f(u.y & 0xFFFFu);
                a3 += bf2f(u.y >> 16);
            }
            if (eb < end) {
                int s = csr_src[eb];
                uint2 u = xb2[(size_t)s * 16 + cc];
                b0 += bf2f(u.x & 0xFFFFu);
                b1 += bf2f(u.x >> 16);
                b2 += bf2f(u.y & 0xFFFFu);
                b3 += bf2f(u.y >> 16);
            }
        }
        a0 += b0; a1 += b1; a2 += b2; a3 += b3;
        a0 += __shfl_xor(a0, 16); a0 += __shfl_xor(a0, 32);
        a1 += __shfl_xor(a1, 16); a1 += __shfl_xor(a1, 32);
        a2 += __shfl_xor(a2, 16); a2 += __shfl_xor(a2, 32);
        a3 += __shfl_xor(a3, 16); a3 += __shfl_xor(a3, 32);
        float inv = 1.f / (float)max(deg, 1);
        if (lane < 16) {
            uint2 o;
            o.x = f2bf_rtn(a0 * inv) | (f2bf_rtn(a1 * inv) << 16);
            o.y = f2bf_rtn(a2 * inv) | (f2bf_rtn(a3 * inv) << 16);
            mb2[(size_t)node * 16 + cc] = o;
        }
    }
}

// ---------------- MFMA linear: h = [mean|self] @ [Wl;Wr] + b, + BN stats ----------------
__global__ __launch_bounds__(256) void k_gemm(const ushort* __restrict__ meanb,
                                              const ushort* __restrict__ selfb,
                                              const ushort* __restrict__ wpk,
                                              const float* __restrict__ bias,
                                              ushort* __restrict__ hout,
                                              float* __restrict__ sums,
                                              float* __restrict__ sumsq) {
    int lane = threadIdx.x & 63;
    int wv = threadIdx.x >> 6;
    int r16 = lane & 15;
    int grp = lane >> 4;
    short8 bfrag[4][4];
    const short8* wp = (const short8*)wpk;
    #pragma unroll
    for (int nt = 0; nt < 4; ++nt)
        #pragma unroll
        for (int kt = 0; kt < 4; ++kt)
            bfrag[nt][kt] = wp[(nt * 4 + kt) * 64 + lane];
    float bcol[4];
    #pragma unroll
    for (int nt = 0; nt < 4; ++nt) bcol[nt] = bias[nt * 16 + r16];
    float sv[4] = {0.f, 0.f, 0.f, 0.f}, qv[4] = {0.f, 0.f, 0.f, 0.f};

    for (int tile = blockIdx.x * 4 + wv; tile < NTILES; tile += gridDim.x * 4) {
        int node = tile * 16 + r16;
        const short8* mrow = (const short8*)(meanb + (size_t)node * HID);
        const short8* srow = (const short8*)(selfb + (size_t)node * HID);
        short8 a[4];
        a[0] = mrow[grp];
        a[1] = mrow[4 + grp];
        a[2] = srow[grp];
        a[3] = srow[4 + grp];
        f32x4 acc[4];
        #pragma unroll
        for (int nt = 0; nt < 4; ++nt) acc[nt] = (f32x4){0.f, 0.f, 0.f, 0.f};
        #pragma unroll
        for (int nt = 0; nt < 4; ++nt)
            #pragma unroll
            for (int kt = 0; kt < 4; ++kt)
                acc[nt] = __builtin_amdgcn_mfma_f32_16x16x32_bf16(a[kt], bfrag[nt][kt],
                                                                  acc[nt], 0, 0, 0);
        #pragma unroll
        for (int nt = 0; nt < 4; ++nt) {
            #pragma unroll
            for (int r = 0; r < 4; ++r) {
                float hv = acc[nt][r] + bcol[nt];
                int rrow = tile * 16 + grp * 4 + r;
                hout[(size_t)rrow * HID + nt * 16 + r16] = (ushort)f2bf_rtn(hv);
                sv[nt] += hv;
                qv[nt] += hv * hv;
            }
        }
    }
    #pragma unroll
    for (int nt = 0; nt < 4; ++nt) {
        float v = sv[nt];
        v += __shfl_xor(v, 16); v += __shfl_xor(v, 32);
        float q = qv[nt];
        q += __shfl_xor(q, 16); q += __shfl_xor(q, 32);
        if (grp == 0) {
            atomicAdd(&sums[nt * 16 + r16], v);
            atomicAdd(&sumsq[nt * 16 + r16], q);
        }
    }
}

// ---------------- BN params ----------------
__global__ void k_bn_params(const float* __restrict__ sums, const float* __restrict__ sumsq,
                            const float* __restrict__ g, const float* __restrict__ be,
                            float* __restrict__ scale, float* __restrict__ shift) {
    int d = threadIdx.x;
    if (d >= HID) return;
    float mu  = sums[d] * (1.f / N_NODES);
    float var = sumsq[d] * (1.f / N_NODES) - mu * mu;
    float sc  = g[d] * rsqrtf(var + BN_EPS);
    scale[d] = sc;
    shift[d] = be[d] - mu * sc;
}

// ---------------- act: relu(h*sc+sh), bf16 -> bf16 ----------------
__global__ void k_act(const ushort* __restrict__ h, const float* __restrict__ scale,
                      const float* __restrict__ shift, ushort* __restrict__ act) {
    int t = blockIdx.x * blockDim.x + threadIdx.x;   // over N*16
    if (t >= N_NODES * 16) return;
    int q = t & 15;
    uint2 u = *(const uint2*)&h[(size_t)t * 4];
    float4 sc = *(const float4*)&scale[q * 4];
    float4 sh = *(const float4*)&shift[q * 4];
    float f0 = fmaxf(fmaf(bf2f(u.x & 0xFFFFu), sc.x, sh.x), 0.f);
    float f1 = fmaxf(fmaf(bf2f(u.x >> 16),     sc.y, sh.y), 0.f);
    float f2 = fmaxf(fmaf(bf2f(u.y & 0xFFFFu), sc.z, sh.z), 0.f);
    float f3 = fmaxf(fmaf(bf2f(u.y >> 16),     sc.w, sh.w), 0.f);
    uint2 o;
    o.x = f2bf_rtn(f0) | (f2bf_rtn(f1) << 16);
    o.y = f2bf_rtn(f2) | (f2bf_rtn(f3) << 16);
    *(uint2*)&act[(size_t)t * 4] = o;
}

// ---------------- pool (fused bn2+relu, bf16 in) + classifier ----------------
__global__ void k_pool(const ushort* __restrict__ h, const int* __restrict__ batch,
                       const float* __restrict__ scale, const float* __restrict__ shift,
                       float* __restrict__ graph_x) {
    int d = threadIdx.x;   // 64 threads
    float sc = scale[d], sh = shift[d];
    int chunk = (N_NODES + gridDim.x - 1) / gridDim.x;
    int a = blockIdx.x * chunk;
    int b = min(a + chunk, N_NODES);
    if (a >= b) return;
    int cur = batch[a];
    float acc = 0.f;
    for (int i = a; i < b; ++i) {
        int g = batch[i];
        if (g != cur) {
            atomicAdd(&graph_x[cur * HID + d], acc);
            acc = 0.f;
            cur = g;
        }
        float v = bf2f((uint32_t)h[(size_t)i * HID + d]);
        acc += fmaxf(fmaf(v, sc, sh), 0.f);
    }
    atomicAdd(&graph_x[cur * HID + d], acc);
}

__global__ void k_cls(const float* __restrict__ graph_x, const float* __restrict__ Wlin,
                      const float* __restrict__ blin, float* __restrict__ out) {
    int idx = blockIdx.x * blockDim.x + threadIdx.x;
    if (idx >= NGRAPH * NCLS) return;
    int g = idx / NCLS, c = idx % NCLS;
    float acc = blin[c];
    #pragma unroll
    for (int k = 0; k < HID; ++k) acc += graph_x[g * HID + k] * Wlin[k * NCLS + c];
    out[idx] = acc;
}

// ---------------- launch ----------------
extern "C" void kernel_launch(void* const* d_in, const int* in_sizes, int n_in,
                              void* d_out, int out_size, void* d_ws, size_t ws_size,
                              hipStream_t stream) {
    const int*   sid   = (const int*)d_in[0];
    const int*   cid   = (const int*)d_in[1];
    const int*   esrc  = (const int*)d_in[2];
    const int*   edst  = esrc + N_EDGES;
    const int*   batch = (const int*)d_in[3];
    const float* sW    = (const float*)d_in[4];
    const float* cW    = (const float*)d_in[5];
    const float* W1l   = (const float*)d_in[6];
    const float* b1    = (const float*)d_in[7];
    const float* W1r   = (const float*)d_in[8];
    const float* g1    = (const float*)d_in[9];
    const float* be1   = (const float*)d_in[10];
    const float* W2l   = (const float*)d_in[11];
    const float* b2    = (const float*)d_in[12];
    const float* W2r   = (const float*)d_in[13];
    const float* g2    = (const float*)d_in[14];
    const float* be2   = (const float*)d_in[15];
    const float* Wlin  = (const float*)d_in[16];
    const float* blin  = (const float*)d_in[17];
    float* out = (float*)d_out;

    // workspace layout (bf16 feature buffers first, all 16B-aligned)
    const size_t FEAT = (size_t)N_NODES * HID;       // elements
    ushort* xb    = (ushort*)d_ws;                   // x0, bf16
    ushort* meanb = xb + FEAT;                       // mean (reused per layer)
    ushort* h1b   = meanb + FEAT;                    // raw h1
    ushort* act1b = h1b + FEAT;                      // relu(bn1(h1))
    ushort* h2b   = act1b + FEAT;                    // raw h2
    ushort* wpk1  = h2b + FEAT;                      // 8192 bf16
    ushort* wpk2  = wpk1 + 8192;
    float* fp     = (float*)(wpk2 + 8192);
    float* sums1  = fp;            float* sumsq1 = sums1 + HID;
    float* sums2  = sumsq1 + HID;  float* sumsq2 = sums2 + HID;
    float* scale1 = sumsq2 + HID;  float* shift1 = scale1 + HID;
    float* scale2 = shift1 + HID;  float* shift2 = scale2 + HID;
    float* graph_x = shift2 + HID;                   // NGRAPH*HID
    int* row_ptr  = (int*)(graph_x + (size_t)NGRAPH * HID);   // N+1
    int* csr_src  = row_ptr + N_NODES + 1;                    // E
    int* bhist    = csr_src + N_EDGES;                        // NB
    int* bucket_off    = bhist + NB;                          // NB+1
    int* bucket_cursor = bucket_off + NB + 1;                 // NB
    // staged aliases meanb (dead before k_gather writes meanb): E uint32 <= FEAT ushort
    uint32_t* staged = (uint32_t*)meanb;

    // ---- zero the accumulated buffers once ----
    hipMemsetAsync(bhist, 0, NB * sizeof(int), stream);
    hipMemsetAsync(sums1, 0, 4 * HID * sizeof(float), stream);
    hipMemsetAsync(graph_x, 0, (size_t)NGRAPH * HID * sizeof(float), stream);

    // ---- embed + weight pack ----
    k_embed<<<(N_NODES * 16 + 255) / 256, 256, 0, stream>>>(sid, cid, sW, cW, xb);
    k_wpack<<<2, 1024, 0, stream>>>(W1l, W1r, W2l, W2r, wpk1, wpk2);

    // ---- bucket CSR build ----
    k_bhist<<<NBLK_E, 256, 0, stream>>>(edst, bhist);
    k_bscan<<<1, 128, 0, stream>>>(bhist, bucket_off, bucket_cursor, row_ptr);
    k_bucket<<<NBLK_E, 256, 0, stream>>>(esrc, edst, bucket_cursor, staged);
    k_place<<<NB, 256, 0, stream>>>(staged, bucket_off, row_ptr, csr_src);

    // ---- layer 1 ----
    k_gather<<<4096, 256, 0, stream>>>(xb, row_ptr, csr_src, meanb);
    k_gemm<<<512, 256, 0, stream>>>(meanb, xb, wpk1, b1, h1b, sums1, sumsq1);
    k_bn_params<<<1, 64, 0, stream>>>(sums1, sumsq1, g1, be1, scale1, shift1);
    k_act<<<(N_NODES * 16 + 255) / 256, 256, 0, stream>>>(h1b, scale1, shift1, act1b);

    // ---- layer 2 ----
    k_gather<<<4096, 256, 0, stream>>>(act1b, row_ptr, csr_src, meanb);
    k_gemm<<<512, 256, 0, stream>>>(meanb, act1b, wpk2, b2, h2b, sums2, sumsq2);
    k_bn_params<<<1, 64, 0, stream>>>(sums2, sumsq2, g2, be2, scale2, shift2);

    // ---- pool (fused bn2+relu) + classifier ----
    k_pool<<<1024, 64, 0, stream>>>(h2b, batch, scale2, shift2, graph_x);
    k_cls<<<(NGRAPH * NCLS + 255) / 256, 256, 0, stream>>>(graph_x, Wlin, blin, out);
}

// Round 7
// 289.559 us; speedup vs baseline: 8.2772x; 1.1618x over previous
//
#include <hip/hip_runtime.h>
#include <stdint.h>

#define N_NODES 100000
#define N_EDGES 1200000
#define HID 64
#define NGRAPH 512
#define NCLS 2
#define BN_EPS 1e-5f

#define NTILES (N_NODES / 16)     // 6250, exact

// bucket sort: 1024-node buckets
#define BKT_SH 10
#define BKT_NODES 1024
#define NB 98                      // ceil(100000/1024)
#define EB_PER_BLK 4096            // edges per k_bucket block (256 thr x 16)
#define NBLK_E 293                 // ceil(1200000/4096)

typedef __attribute__((ext_vector_type(8))) short short8;   // 8 bf16 = 4 VGPRs
typedef __attribute__((ext_vector_type(4))) float f32x4;

__device__ inline float bf2f(uint32_t hi16) {
    uint32_t u = hi16 << 16;
    return __builtin_bit_cast(float, u);
}
__device__ inline uint32_t f2bf_rtn(float f) {             // round-to-nearest-even
    uint32_t u = __builtin_bit_cast(uint32_t, f);
    return (u + 0x7FFFu + ((u >> 16) & 1u)) >> 16;
}

// ---------------- node code: sid | cid<<4 (7 bits) ----------------
__global__ void k_code(const int* __restrict__ sid, const int* __restrict__ cid,
                       unsigned char* __restrict__ code8) {
    int i = blockIdx.x * blockDim.x + threadIdx.x;
    if (i < N_NODES) code8[i] = (unsigned char)(sid[i] | (cid[i] << 4));
}

// ---------------- projected embedding tables (layer-1 linearity trick) ----------------
// tblL[c][d] = sum_k emb[c][k]*W1l[k][d];  tblR[c][d] = sum_k emb[c][k]*W1r[k][d] + b1[d]
// where emb[c][k] = sW[c&15][k] + cW[c>>4][k].  bf16 output.
__global__ __launch_bounds__(256) void k_tab(const float* __restrict__ sW,
                                             const float* __restrict__ cW,
                                             const float* __restrict__ W1l,
                                             const float* __restrict__ W1r,
                                             const float* __restrict__ b1,
                                             ushort* __restrict__ tblL,
                                             ushort* __restrict__ tblR) {
    int gid = blockIdx.x * 256 + threadIdx.x;   // 16384
    int which = gid >> 13;
    int c = (gid >> 6) & 127;
    int d = gid & 63;
    int s = c & 15, cl = c >> 4;
    const float* W = which ? W1r : W1l;
    float acc = which ? b1[d] : 0.f;
    #pragma unroll 8
    for (int k = 0; k < 64; ++k)
        acc += (sW[s * 64 + k] + cW[cl * 64 + k]) * W[k * 64 + d];
    (which ? tblR : tblL)[c * 64 + d] = (ushort)f2bf_rtn(acc);
}

// ---------------- bucket CSR build ----------------
__global__ __launch_bounds__(256) void k_bhist(const int* __restrict__ dst,
                                               int* __restrict__ bhist) {
    __shared__ int h[NB];
    int tid = threadIdx.x;
    if (tid < NB) h[tid] = 0;
    __syncthreads();
    int base = blockIdx.x * EB_PER_BLK;
    #pragma unroll
    for (int i = 0; i < 16; ++i) {
        int e = base + i * 256 + tid;
        if (e < N_EDGES) atomicAdd(&h[dst[e] >> BKT_SH], 1);
    }
    __syncthreads();
    if (tid < NB) atomicAdd(&bhist[tid], h[tid]);
}

__global__ __launch_bounds__(128) void k_bscan(const int* __restrict__ bhist,
                                               int* __restrict__ bucket_off,
                                               int* __restrict__ bucket_cursor,
                                               int* __restrict__ row_ptr) {
    __shared__ int sh[128];
    int t = threadIdx.x;
    int v = (t < NB) ? bhist[t] : 0;
    sh[t] = v;
    __syncthreads();
    #pragma unroll
    for (int off = 1; off < 128; off <<= 1) {
        int cur = sh[t];
        int u = (t >= off) ? sh[t - off] : 0;
        __syncthreads();
        sh[t] = cur + u;
        __syncthreads();
    }
    if (t < NB) {
        int ex = sh[t] - v;
        bucket_off[t] = ex;
        bucket_cursor[t] = ex;
    }
    if (t == 0) {
        bucket_off[NB] = N_EDGES;
        row_ptr[N_NODES] = N_EDGES;
    }
}

__global__ __launch_bounds__(256) void k_bucket(const int* __restrict__ src,
                                                const int* __restrict__ dst,
                                                int* __restrict__ bucket_cursor,
                                                uint32_t* __restrict__ staged) {
    __shared__ int h[NB];
    __shared__ int cur[NB];
    int tid = threadIdx.x;
    if (tid < NB) h[tid] = 0;
    __syncthreads();
    uint32_t pk[16];
    int bk[16];
    int base = blockIdx.x * EB_PER_BLK;
    #pragma unroll
    for (int i = 0; i < 16; ++i) {
        int e = base + i * 256 + tid;
        if (e < N_EDGES) {
            int s = src[e], d = dst[e];
            bk[i] = d >> BKT_SH;
            pk[i] = ((uint32_t)s << BKT_SH) | (uint32_t)(d & (BKT_NODES - 1));
            atomicAdd(&h[bk[i]], 1);
        } else {
            bk[i] = -1;
        }
    }
    __syncthreads();
    if (tid < NB) cur[tid] = atomicAdd(&bucket_cursor[tid], h[tid]);
    __syncthreads();
    #pragma unroll
    for (int i = 0; i < 16; ++i) {
        if (bk[i] >= 0) {
            int slot = atomicAdd(&cur[bk[i]], 1);
            staged[slot] = pk[i];
        }
    }
}

__global__ __launch_bounds__(256) void k_place(const uint32_t* __restrict__ staged,
                                               const int* __restrict__ bucket_off,
                                               int* __restrict__ row_ptr,
                                               int* __restrict__ csr_src) {
    __shared__ int hist[BKT_NODES];
    __shared__ int cursor[BKT_NODES];
    __shared__ int part[256];
    int b = blockIdx.x;
    int tid = threadIdx.x;
    int nodes0 = b << BKT_SH;
    int nn = min(BKT_NODES, N_NODES - nodes0);
    int ebeg = bucket_off[b], eend = bucket_off[b + 1];
    #pragma unroll
    for (int j = 0; j < 4; ++j) hist[tid * 4 + j] = 0;
    __syncthreads();
    for (int e = ebeg + tid; e < eend; e += 256)
        atomicAdd(&hist[staged[e] & (BKT_NODES - 1)], 1);
    __syncthreads();
    int c0 = hist[tid * 4 + 0], c1 = hist[tid * 4 + 1];
    int c2 = hist[tid * 4 + 2], c3 = hist[tid * 4 + 3];
    int s = c0 + c1 + c2 + c3;
    part[tid] = s;
    __syncthreads();
    #pragma unroll
    for (int off = 1; off < 256; off <<= 1) {
        int curv = part[tid];
        int u = (tid >= off) ? part[tid - off] : 0;
        __syncthreads();
        part[tid] = curv + u;
        __syncthreads();
    }
    int basev = ebeg + part[tid] - s;
    int e0 = basev, e1 = e0 + c0, e2 = e1 + c1, e3 = e2 + c2;
    cursor[tid * 4 + 0] = e0; cursor[tid * 4 + 1] = e1;
    cursor[tid * 4 + 2] = e2; cursor[tid * 4 + 3] = e3;
    #pragma unroll
    for (int j = 0; j < 4; ++j) {
        int i = tid * 4 + j;
        if (i < nn) row_ptr[nodes0 + i] = cursor[i];
    }
    __syncthreads();
    for (int e = ebeg + tid; e < eend; e += 256) {
        uint32_t pk = staged[e];
        int slot = atomicAdd(&cursor[pk & (BKT_NODES - 1)], 1);
        csr_src[slot] = (int)(pk >> BKT_SH);
    }
}

// ---------------- layer 1: table-gather -> h1 (bf16) + BN stats ----------------
// h1[i] = (sum_j tblL[code[src_j]]) / deg + tblR[code[i]]   (b1 folded into tblR)
__global__ __launch_bounds__(256) void k_gather1(
    const int* __restrict__ row_ptr, const int* __restrict__ csr_src,
    const unsigned char* __restrict__ code8,
    const ushort* __restrict__ tblL, const ushort* __restrict__ tblR,
    ushort* __restrict__ h1b, float* __restrict__ sums, float* __restrict__ sumsq) {
    __shared__ float lsum[4][64];
    __shared__ float lsq[4][64];
    int tid = threadIdx.x, lane = tid & 63, wv = tid >> 6;
    int g = lane >> 4, cc = lane & 15;
    const uint2* tL = (const uint2*)tblL;
    const uint2* tR = (const uint2*)tblR;
    uint2* h1_2 = (uint2*)h1b;
    float sv0 = 0, sv1 = 0, sv2 = 0, sv3 = 0;
    float qv0 = 0, qv1 = 0, qv2 = 0, qv3 = 0;
    for (int node = blockIdx.x * 4 + wv; node < N_NODES; node += gridDim.x * 4) {
        int beg = row_ptr[node], end = row_ptr[node + 1];
        int deg = end - beg;
        float a0[4] = {0, 0, 0, 0}, a1[4] = {0, 0, 0, 0};
        float a2[4] = {0, 0, 0, 0}, a3[4] = {0, 0, 0, 0};
        int iters = (deg + 15) >> 4;
        for (int it = 0; it < iters; ++it) {
            int ebase = beg + it * 16 + g;
            #pragma unroll
            for (int u = 0; u < 4; ++u) {
                int e = ebase + u * 4;
                if (e < end) {
                    int sn = csr_src[e];
                    int c = code8[sn];
                    uint2 t = tL[c * 16 + cc];
                    a0[u] += bf2f(t.x & 0xFFFFu);
                    a1[u] += bf2f(t.x >> 16);
                    a2[u] += bf2f(t.y & 0xFFFFu);
                    a3[u] += bf2f(t.y >> 16);
                }
            }
        }
        float m0 = (a0[0] + a0[1]) + (a0[2] + a0[3]);
        float m1 = (a1[0] + a1[1]) + (a1[2] + a1[3]);
        float m2 = (a2[0] + a2[1]) + (a2[2] + a2[3]);
        float m3 = (a3[0] + a3[1]) + (a3[2] + a3[3]);
        m0 += __shfl_xor(m0, 16); m0 += __shfl_xor(m0, 32);
        m1 += __shfl_xor(m1, 16); m1 += __shfl_xor(m1, 32);
        m2 += __shfl_xor(m2, 16); m2 += __shfl_xor(m2, 32);
        m3 += __shfl_xor(m3, 16); m3 += __shfl_xor(m3, 32);
        if (lane < 16) {
            float inv = 1.f / (float)max(deg, 1);
            int c = code8[node];
            uint2 tr = tR[c * 16 + cc];
            float h0 = fmaf(m0, inv, bf2f(tr.x & 0xFFFFu));
            float h1 = fmaf(m1, inv, bf2f(tr.x >> 16));
            float h2 = fmaf(m2, inv, bf2f(tr.y & 0xFFFFu));
            float h3 = fmaf(m3, inv, bf2f(tr.y >> 16));
            uint2 o;
            o.x = f2bf_rtn(h0) | (f2bf_rtn(h1) << 16);
            o.y = f2bf_rtn(h2) | (f2bf_rtn(h3) << 16);
            h1_2[(size_t)node * 16 + cc] = o;
            sv0 += h0; qv0 += h0 * h0;
            sv1 += h1; qv1 += h1 * h1;
            sv2 += h2; qv2 += h2 * h2;
            sv3 += h3; qv3 += h3 * h3;
        }
    }
    if (lane < 16) {
        lsum[wv][cc * 4 + 0] = sv0; lsum[wv][cc * 4 + 1] = sv1;
        lsum[wv][cc * 4 + 2] = sv2; lsum[wv][cc * 4 + 3] = sv3;
        lsq[wv][cc * 4 + 0] = qv0; lsq[wv][cc * 4 + 1] = qv1;
        lsq[wv][cc * 4 + 2] = qv2; lsq[wv][cc * 4 + 3] = qv3;
    }
    __syncthreads();
    if (wv == 0) {
        int d = lane;
        float S = lsum[0][d] + lsum[1][d] + lsum[2][d] + lsum[3][d];
        float Q = lsq[0][d] + lsq[1][d] + lsq[2][d] + lsq[3][d];
        atomicAdd(&sums[d], S);
        atomicAdd(&sumsq[d], Q);
    }
}

// ---------------- BN params ----------------
__global__ void k_bn_params(const float* __restrict__ sums, const float* __restrict__ sumsq,
                            const float* __restrict__ g, const float* __restrict__ be,
                            float* __restrict__ scale, float* __restrict__ shift) {
    int d = threadIdx.x;
    if (d >= HID) return;
    float mu  = sums[d] * (1.f / N_NODES);
    float var = sumsq[d] * (1.f / N_NODES) - mu * mu;
    float sc  = g[d] * rsqrtf(var + BN_EPS);
    scale[d] = sc;
    shift[d] = be[d] - mu * sc;
}

// ---------------- layer-2 gather: relu(bn1(h1[src])) mean -> bf16 ----------------
__global__ __launch_bounds__(256) void k_gather2(
    const ushort* __restrict__ h1b, const int* __restrict__ row_ptr,
    const int* __restrict__ csr_src,
    const float* __restrict__ scale, const float* __restrict__ shift,
    ushort* __restrict__ meanb) {
    int lane = threadIdx.x & 63, wv = threadIdx.x >> 6;
    int g = lane >> 4, cc = lane & 15;
    float4 sc = *(const float4*)&scale[cc * 4];
    float4 sh = *(const float4*)&shift[cc * 4];
    const uint2* x2 = (const uint2*)h1b;
    uint2* mb2 = (uint2*)meanb;
    for (int node = blockIdx.x * 4 + wv; node < N_NODES; node += gridDim.x * 4) {
        int beg = row_ptr[node], end = row_ptr[node + 1];
        int deg = end - beg;
        float a0[4] = {0, 0, 0, 0}, a1[4] = {0, 0, 0, 0};
        float a2[4] = {0, 0, 0, 0}, a3[4] = {0, 0, 0, 0};
        int iters = (deg + 15) >> 4;
        for (int it = 0; it < iters; ++it) {
            int ebase = beg + it * 16 + g;
            #pragma unroll
            for (int u = 0; u < 4; ++u) {
                int e = ebase + u * 4;
                if (e < end) {
                    int sn = csr_src[e];
                    uint2 t = x2[(size_t)sn * 16 + cc];
                    a0[u] += fmaxf(fmaf(bf2f(t.x & 0xFFFFu), sc.x, sh.x), 0.f);
                    a1[u] += fmaxf(fmaf(bf2f(t.x >> 16),     sc.y, sh.y), 0.f);
                    a2[u] += fmaxf(fmaf(bf2f(t.y & 0xFFFFu), sc.z, sh.z), 0.f);
                    a3[u] += fmaxf(fmaf(bf2f(t.y >> 16),     sc.w, sh.w), 0.f);
                }
            }
        }
        float m0 = (a0[0] + a0[1]) + (a0[2] + a0[3]);
        float m1 = (a1[0] + a1[1]) + (a1[2] + a1[3]);
        float m2 = (a2[0] + a2[1]) + (a2[2] + a2[3]);
        float m3 = (a3[0] + a3[1]) + (a3[2] + a3[3]);
        m0 += __shfl_xor(m0, 16); m0 += __shfl_xor(m0, 32);
        m1 += __shfl_xor(m1, 16); m1 += __shfl_xor(m1, 32);
        m2 += __shfl_xor(m2, 16); m2 += __shfl_xor(m2, 32);
        m3 += __shfl_xor(m3, 16); m3 += __shfl_xor(m3, 32);
        if (lane < 16) {
            float inv = 1.f / (float)max(deg, 1);
            uint2 o;
            o.x = f2bf_rtn(m0 * inv) | (f2bf_rtn(m1 * inv) << 16);
            o.y = f2bf_rtn(m2 * inv) | (f2bf_rtn(m3 * inv) << 16);
            mb2[(size_t)node * 16 + cc] = o;
        }
    }
}

// ---------------- pack layer-2 weights into MFMA B-fragments ----------------
__global__ void k_wpack(const float* __restrict__ Wl, const float* __restrict__ Wr,
                        ushort* __restrict__ wpk) {
    int gid = blockIdx.x * blockDim.x + threadIdx.x;   // 1024
    if (gid >= 1024) return;
    int tile = gid >> 6;       // 0..15 = nt*4+kt
    int lane = gid & 63;
    int nt = tile >> 2, kt = tile & 3;
    #pragma unroll
    for (int j = 0; j < 8; ++j) {
        int k = kt * 32 + (lane >> 4) * 8 + j;
        int n = nt * 16 + (lane & 15);
        float v = (k < 64) ? Wl[k * HID + n] : Wr[(k - 64) * HID + n];
        wpk[(size_t)(tile * 64 + lane) * 8 + j] = (ushort)f2bf_rtn(v);
    }
}

// ---------------- layer-2 MFMA: h2 = [mean2 | act1] @ [W2l;W2r] + b2, + BN stats ----
// act1 = relu(bn1(h1)) applied inline to the self-part A-fragments.
__global__ __launch_bounds__(256) void k_gemm2(
    const ushort* __restrict__ meanb, const ushort* __restrict__ h1b,
    const ushort* __restrict__ wpk, const float* __restrict__ bias,
    const float* __restrict__ scale, const float* __restrict__ shift,
    ushort* __restrict__ hout, float* __restrict__ sums, float* __restrict__ sumsq) {
    __shared__ float lsum[4][64];
    __shared__ float lsq[4][64];
    int lane = threadIdx.x & 63;
    int wv = threadIdx.x >> 6;
    int r16 = lane & 15;
    int grp = lane >> 4;
    short8 bfrag[4][4];
    const short8* wp = (const short8*)wpk;
    #pragma unroll
    for (int nt = 0; nt < 4; ++nt)
        #pragma unroll
        for (int kt = 0; kt < 4; ++kt)
            bfrag[nt][kt] = wp[(nt * 4 + kt) * 64 + lane];
    float bcol[4];
    #pragma unroll
    for (int nt = 0; nt < 4; ++nt) bcol[nt] = bias[nt * 16 + r16];
    // act params for the self dims this lane supplies
    float4 scA0 = *(const float4*)&scale[grp * 8];
    float4 scA1 = *(const float4*)&scale[grp * 8 + 4];
    float4 shA0 = *(const float4*)&shift[grp * 8];
    float4 shA1 = *(const float4*)&shift[grp * 8 + 4];
    float4 scB0 = *(const float4*)&scale[32 + grp * 8];
    float4 scB1 = *(const float4*)&scale[32 + grp * 8 + 4];
    float4 shB0 = *(const float4*)&shift[32 + grp * 8];
    float4 shB1 = *(const float4*)&shift[32 + grp * 8 + 4];

    float sv[4] = {0.f, 0.f, 0.f, 0.f}, qv[4] = {0.f, 0.f, 0.f, 0.f};
    int tile = blockIdx.x * 4 + wv;
    if (tile < NTILES) {
        int node = tile * 16 + r16;
        const short8* mrow = (const short8*)(meanb + (size_t)node * HID);
        short8 a[4];
        a[0] = mrow[grp];
        a[1] = mrow[4 + grp];
        const uint2* s2 = (const uint2*)(h1b + (size_t)node * HID);
        uint2 u0 = s2[grp * 2], u1 = s2[grp * 2 + 1];
        uint2 u2 = s2[8 + grp * 2], u3 = s2[9 + grp * 2];
        short8 a2v, a3v;
        a2v[0] = (short)f2bf_rtn(fmaxf(fmaf(bf2f(u0.x & 0xFFFFu), scA0.x, shA0.x), 0.f));
        a2v[1] = (short)f2bf_rtn(fmaxf(fmaf(bf2f(u0.x >> 16),     scA0.y, shA0.y), 0.f));
        a2v[2] = (short)f2bf_rtn(fmaxf(fmaf(bf2f(u0.y & 0xFFFFu), scA0.z, shA0.z), 0.f));
        a2v[3] = (short)f2bf_rtn(fmaxf(fmaf(bf2f(u0.y >> 16),     scA0.w, shA0.w), 0.f));
        a2v[4] = (short)f2bf_rtn(fmaxf(fmaf(bf2f(u1.x & 0xFFFFu), scA1.x, shA1.x), 0.f));
        a2v[5] = (short)f2bf_rtn(fmaxf(fmaf(bf2f(u1.x >> 16),     scA1.y, shA1.y), 0.f));
        a2v[6] = (short)f2bf_rtn(fmaxf(fmaf(bf2f(u1.y & 0xFFFFu), scA1.z, shA1.z), 0.f));
        a2v[7] = (short)f2bf_rtn(fmaxf(fmaf(bf2f(u1.y >> 16),     scA1.w, shA1.w), 0.f));
        a3v[0] = (short)f2bf_rtn(fmaxf(fmaf(bf2f(u2.x & 0xFFFFu), scB0.x, shB0.x), 0.f));
        a3v[1] = (short)f2bf_rtn(fmaxf(fmaf(bf2f(u2.x >> 16),     scB0.y, shB0.y), 0.f));
        a3v[2] = (short)f2bf_rtn(fmaxf(fmaf(bf2f(u2.y & 0xFFFFu), scB0.z, shB0.z), 0.f));
        a3v[3] = (short)f2bf_rtn(fmaxf(fmaf(bf2f(u2.y >> 16),     scB0.w, shB0.w), 0.f));
        a3v[4] = (short)f2bf_rtn(fmaxf(fmaf(bf2f(u3.x & 0xFFFFu), scB1.x, shB1.x), 0.f));
        a3v[5] = (short)f2bf_rtn(fmaxf(fmaf(bf2f(u3.x >> 16),     scB1.y, shB1.y), 0.f));
        a3v[6] = (short)f2bf_rtn(fmaxf(fmaf(bf2f(u3.y & 0xFFFFu), scB1.z, shB1.z), 0.f));
        a3v[7] = (short)f2bf_rtn(fmaxf(fmaf(bf2f(u3.y >> 16),     scB1.w, shB1.w), 0.f));
        a[2] = a2v;
        a[3] = a3v;
        f32x4 acc[4];
        #pragma unroll
        for (int nt = 0; nt < 4; ++nt) acc[nt] = (f32x4){0.f, 0.f, 0.f, 0.f};
        #pragma unroll
        for (int nt = 0; nt < 4; ++nt)
            #pragma unroll
            for (int kt = 0; kt < 4; ++kt)
                acc[nt] = __builtin_amdgcn_mfma_f32_16x16x32_bf16(a[kt], bfrag[nt][kt],
                                                                  acc[nt], 0, 0, 0);
        #pragma unroll
        for (int nt = 0; nt < 4; ++nt) {
            #pragma unroll
            for (int r = 0; r < 4; ++r) {
                float hv = acc[nt][r] + bcol[nt];
                int rrow = tile * 16 + grp * 4 + r;
                hout[(size_t)rrow * HID + nt * 16 + r16] = (ushort)f2bf_rtn(hv);
                sv[nt] += hv;
                qv[nt] += hv * hv;
            }
        }
    }
    // stats: reduce across grp, then across waves via LDS, 128 atomics/block
    #pragma unroll
    for (int nt = 0; nt < 4; ++nt) {
        float v = sv[nt];
        v += __shfl_xor(v, 16); v += __shfl_xor(v, 32);
        float q = qv[nt];
        q += __shfl_xor(q, 16); q += __shfl_xor(q, 32);
        if (grp == 0) {
            lsum[wv][nt * 16 + r16] = v;
            lsq[wv][nt * 16 + r16] = q;
        }
    }
    __syncthreads();
    if (wv == 0) {
        int d = lane;
        float S = lsum[0][d] + lsum[1][d] + lsum[2][d] + lsum[3][d];
        float Q = lsq[0][d] + lsq[1][d] + lsq[2][d] + lsq[3][d];
        atomicAdd(&sums[d], S);
        atomicAdd(&sumsq[d], Q);
    }
}

// ---------------- pool (fused bn2+relu, bf16 in) + classifier ----------------
__global__ __launch_bounds__(256) void k_pool(const ushort* __restrict__ h,
                                              const int* __restrict__ batch,
                                              const float* __restrict__ scale,
                                              const float* __restrict__ shift,
                                              float* __restrict__ graph_x) {
    int wv = threadIdx.x >> 6, d = threadIdx.x & 63;
    float sc = scale[d], sh = shift[d];
    const int NCHUNK = 4096;
    int cidx = blockIdx.x * 4 + wv;
    int chunk = (N_NODES + NCHUNK - 1) / NCHUNK;   // 25
    int a = cidx * chunk;
    int b = min(a + chunk, N_NODES);
    if (a >= b) return;
    int cur = batch[a];
    float acc = 0.f;
    for (int i = a; i < b; ++i) {
        int g = batch[i];
        if (g != cur) {
            atomicAdd(&graph_x[cur * HID + d], acc);
            acc = 0.f;
            cur = g;
        }
        float v = bf2f((uint32_t)h[(size_t)i * HID + d]);
        acc += fmaxf(fmaf(v, sc, sh), 0.f);
    }
    atomicAdd(&graph_x[cur * HID + d], acc);
}

__global__ void k_cls(const float* __restrict__ graph_x, const float* __restrict__ Wlin,
                      const float* __restrict__ blin, float* __restrict__ out) {
    int idx = blockIdx.x * blockDim.x + threadIdx.x;
    if (idx >= NGRAPH * NCLS) return;
    int g = idx / NCLS, c = idx % NCLS;
    float acc = blin[c];
    #pragma unroll
    for (int k = 0; k < HID; ++k) acc += graph_x[g * HID + k] * Wlin[k * NCLS + c];
    out[idx] = acc;
}

// ---------------- launch ----------------
extern "C" void kernel_launch(void* const* d_in, const int* in_sizes, int n_in,
                              void* d_out, int out_size, void* d_ws, size_t ws_size,
                              hipStream_t stream) {
    const int*   sid   = (const int*)d_in[0];
    const int*   cid   = (const int*)d_in[1];
    const int*   esrc  = (const int*)d_in[2];
    const int*   edst  = esrc + N_EDGES;
    const int*   batch = (const int*)d_in[3];
    const float* sW    = (const float*)d_in[4];
    const float* cW    = (const float*)d_in[5];
    const float* W1l   = (const float*)d_in[6];
    const float* b1    = (const float*)d_in[7];
    const float* W1r   = (const float*)d_in[8];
    const float* g1    = (const float*)d_in[9];
    const float* be1   = (const float*)d_in[10];
    const float* W2l   = (const float*)d_in[11];
    const float* b2    = (const float*)d_in[12];
    const float* W2r   = (const float*)d_in[13];
    const float* g2    = (const float*)d_in[14];
    const float* be2   = (const float*)d_in[15];
    const float* Wlin  = (const float*)d_in[16];
    const float* blin  = (const float*)d_in[17];
    float* out = (float*)d_out;

    // workspace layout
    const size_t FEAT = (size_t)N_NODES * HID;        // elements
    ushort* meanb = (ushort*)d_ws;                    // mean (layer 2); staged aliases this
    ushort* h1b   = meanb + FEAT;                     // raw h1 bf16
    ushort* h2b   = h1b + FEAT;                       // raw h2 bf16
    ushort* wpk2  = h2b + FEAT;                       // 8192
    ushort* tblL  = wpk2 + 8192;                      // 128*64
    ushort* tblR  = tblL + 8192;                      // 128*64
    float* fp     = (float*)(tblR + 8192);
    float* sums1  = fp;            float* sumsq1 = sums1 + HID;
    float* sums2  = sumsq1 + HID;  float* sumsq2 = sums2 + HID;
    float* scale1 = sumsq2 + HID;  float* shift1 = scale1 + HID;
    float* scale2 = shift1 + HID;  float* shift2 = scale2 + HID;
    float* graph_x = shift2 + HID;                    // NGRAPH*HID
    int* row_ptr  = (int*)(graph_x + (size_t)NGRAPH * HID);   // N+1
    int* csr_src  = row_ptr + N_NODES + 1;                    // E
    int* bhist    = csr_src + N_EDGES;                        // NB
    int* bucket_off    = bhist + NB;                          // NB+1
    int* bucket_cursor = bucket_off + NB + 1;                 // NB
    unsigned char* code8 = (unsigned char*)(bucket_cursor + NB);   // N bytes
    uint32_t* staged = (uint32_t*)meanb;              // E uint32 <= FEAT ushort

    // ---- zero accumulated buffers ----
    hipMemsetAsync(bhist, 0, NB * sizeof(int), stream);
    hipMemsetAsync(sums1, 0, 4 * HID * sizeof(float), stream);
    hipMemsetAsync(graph_x, 0, (size_t)NGRAPH * HID * sizeof(float), stream);

    // ---- precompute: codes, projected tables, packed weights ----
    k_code<<<(N_NODES + 255) / 256, 256, 0, stream>>>(sid, cid, code8);
    k_tab<<<64, 256, 0, stream>>>(sW, cW, W1l, W1r, b1, tblL, tblR);
    k_wpack<<<4, 256, 0, stream>>>(W2l, W2r, wpk2);

    // ---- bucket CSR build ----
    k_bhist<<<NBLK_E, 256, 0, stream>>>(edst, bhist);
    k_bscan<<<1, 128, 0, stream>>>(bhist, bucket_off, bucket_cursor, row_ptr);
    k_bucket<<<NBLK_E, 256, 0, stream>>>(esrc, edst, bucket_cursor, staged);
    k_place<<<NB, 256, 0, stream>>>(staged, bucket_off, row_ptr, csr_src);

    // ---- layer 1 (table gather, no GEMM) ----
    k_gather1<<<2048, 256, 0, stream>>>(row_ptr, csr_src, code8, tblL, tblR,
                                        h1b, sums1, sumsq1);
    k_bn_params<<<1, 64, 0, stream>>>(sums1, sumsq1, g1, be1, scale1, shift1);

    // ---- layer 2 ----
    k_gather2<<<4096, 256, 0, stream>>>(h1b, row_ptr, csr_src, scale1, shift1, meanb);
    k_gemm2<<<(NTILES + 3) / 4, 256, 0, stream>>>(meanb, h1b, wpk2, b2, scale1, shift1,
                                                  h2b, sums2, sumsq2);
    k_bn_params<<<1, 64, 0, stream>>>(sums2, sumsq2, g2, be2, scale2, shift2);

    // ---- pool (fused bn2+relu) + classifier ----
    k_pool<<<1024, 256, 0, stream>>>(h2b, batch, scale2, shift2, graph_x);
    k_cls<<<(NGRAPH * NCLS + 255) / 256, 256, 0, stream>>>(graph_x, Wlin, blin, out);
}